// Round 4
// baseline (198.867 us; speedup 1.0000x reference)
//
#include <hip/hip_runtime.h>
#include <stdint.h>

// ---------------------------------------------------------------------------
// MADE flow layer, f32 I/O.
//   h  = relu(zp @ (W1*M1) + b1)     GEMM1: M=4096 N=4096 K=1024 (int8)
//   res= h @ (W2*M2) + b2            GEMM2: M=4096 N=2048 K=4096 (MX-fp8)
//   x[:, perm[i]] = zp*exp(log_s)+mu ; log_det exact via fused h.wsum2
//
// R19 change (vs R18 PASS @189.2us): gemm2f counted-vmcnt ring-3 pipeline.
// R18's gemm2f (45.3us) hit 93% of the m97-structure MX ceiling (m148:
// 1628 TF); the stall is the per-K-step vmcnt(0) drain at __syncthreads
// (m233: stage+vmcnt+bar = 72% of 2-phase time). New gemm2f: 256 rows x
// 64 pairs, 512 thr (8 waves 4Mx2P), 48KB/K-tile, RING-3 LDS (144KB,
// 1 block/CU), prefetch depth 2 with counted waits:
//   loop t: vmcnt(6) [tile t's 6 loads done, t+1/t+2 stay in flight]
//           -> s_barrier -> STAGE(buf[(t+2)%3]) -> ds_read buf[t%3]
//           -> setprio(1) -> 16 MFMA -> setprio(0);  peeled t=31: vmcnt(0).
// Overwrite race ruled out: buf[(t+2)%3]=buf[(t-1)%3]; every wave's
// ds_reads of t-1 complete (lgkmcnt before MFMA) before it reaches the
// iter-t barrier, which precedes any STAGE. T5 setprio: counted pipeline
// gives waves stage/MFMA role diversity (m218b precondition).
// Arithmetic bit-identical to R18 (same kt order/epilogue math).
// prep_k / gemm1_k untouched (validated).
// ---------------------------------------------------------------------------

typedef float   f32x4  __attribute__((ext_vector_type(4)));
typedef int     i32x4  __attribute__((ext_vector_type(4)));
typedef int     i32x8  __attribute__((ext_vector_type(8)));

__device__ __forceinline__ uint8_t f2fp8(float f) {
    int p = __builtin_amdgcn_cvt_pk_fp8_f32(f, 0.0f, 0, false);
    return (uint8_t)(p & 0xff);
}
__device__ __forceinline__ int8_t f2i8(float v, float s) {
    float q = rintf(v * s);
    q = fminf(fmaxf(q, -127.0f), 127.0f);
    return (int8_t)q;
}

#define GLD16(g, l)                                                          \
    __builtin_amdgcn_global_load_lds(                                        \
        (const __attribute__((address_space(1))) uint32_t*)(g),              \
        (__attribute__((address_space(3))) uint32_t*)(l), 16, 0, 0)

#define MFMA_MX(a, b, c)                                                     \
    __builtin_amdgcn_mfma_scale_f32_16x16x128_f8f6f4(                        \
        (a), (b), (c), 0, 0, 0, 0x7F7F7F7F, 0, 0x7F7F7F7F)

// ---------------------------------------------------------------------------
// prep_k: fused preprocessing, block-role partitioned (unchanged from R17).
// ---------------------------------------------------------------------------
__global__ __launch_bounds__(256) void prep_k(
    const float* __restrict__ W1, int8_t* __restrict__ W1mT,
    const float* __restrict__ W2, uint8_t* __restrict__ W2mT,
    float* __restrict__ ws2p,
    const float* __restrict__ z, const int* __restrict__ perm,
    int8_t* __restrict__ zp, float* __restrict__ ld,
    int D, int H, int B) {
    const int bx  = blockIdx.x;
    const int tid = threadIdx.x;
    const int NB1 = (H / 64) * (D / 64);          // 1024
    const int NB2 = (2 * D / 64) * (H / 64);      // 2048

    if (bx < NB1) {
        // ---- mt1: masked transpose W1 -> int8 ----
        __shared__ int8_t t[64][68];
        const int c0 = (bx % (H / 64)) * 64;      // col in [0,H)
        const int r0 = (bx / (H / 64)) * 64;      // row in [0,D)
        const int tx = tid & 63, ty = tid >> 6;

        const int fid = bx * 256 + tid;
        if (fid < B) ld[fid] = 0.0f;

        for (int rr = ty; rr < 64; rr += 4) {
            const int r = r0 + rr, c = c0 + tx;
            float v = W1[(size_t)r * H + c];
            t[rr][tx] = ((c % (D - 1)) >= r) ? f2i8(v, 1024.0f) : (int8_t)0;
        }
        __syncthreads();
#pragma unroll
        for (int pass = 0; pass < 2; pass++) {
            const int cc = pass * 32 + (tid >> 3);
            const int j0 = (tid & 7) * 8;
            union { int8_t b[8]; uint64_t q; } v;
#pragma unroll
            for (int j = 0; j < 8; j++) v.b[j] = t[j0 + j][cc];
            *(uint64_t*)&W1mT[(size_t)(c0 + cc) * D + r0 + j0] = v.q;
        }
    } else if (bx < NB1 + NB2) {
        // ---- mt2: masked transpose W2 -> fp8 + ws2 partial row-sums ----
        __shared__ uint8_t t[64][68];
        const int idx = bx - NB1;
        const int c0 = (idx % (2 * D / 64)) * 64; // col in [0,2D)
        const int r0 = (idx / (2 * D / 64)) * 64; // row in [0,H)
        const int tx = tid & 63, ty = tid >> 6;
        const bool second = (c0 >= D);
        const int cb = (c0 - D) >> 6;             // partial slot [0,16)

        for (int rr = ty; rr < 64; rr += 4) {
            const int r = r0 + rr, c = c0 + tx;
            float v = W2[(size_t)r * 2 * D + c];
            bool keep = ((c % D) > (r % (D - 1)));
            t[rr][tx] = keep ? f2fp8(v * 256.0f) : (uint8_t)0;
            if (second) {
                float s = keep ? v : 0.0f;
#pragma unroll
                for (int o = 32; o > 0; o >>= 1) s += __shfl_down(s, o, 64);
                if (tx == 0) ws2p[(size_t)cb * H + r] = s;
            }
        }
        __syncthreads();
#pragma unroll
        for (int pass = 0; pass < 2; pass++) {
            const int cc = pass * 32 + (tid >> 3);
            const int j0 = (tid & 7) * 8;
            union { uint8_t b[8]; uint64_t q; } v;
#pragma unroll
            for (int j = 0; j < 8; j++) v.b[j] = t[j0 + j][cc];
            *(uint64_t*)&W2mT[(size_t)(c0 + cc) * H + r0 + j0] = v.q;
        }
    } else {
        // ---- perm+quant: 2 rows/block, 4 elems/thread/row ----
        const int bp = bx - NB1 - NB2;
        const int i0 = tid * 4;                   // D = 1024 = 256*4
        const int4 p4 = *(const int4*)(perm + i0);
#pragma unroll
        for (int rr = 0; rr < 2; rr++) {
            const int b = bp * 2 + rr;
            const float* zr = z + (size_t)b * D;
            union { int8_t b4[4]; uint32_t u; } q;
            q.b4[0] = f2i8(zr[p4.x], 32.0f);
            q.b4[1] = f2i8(zr[p4.y], 32.0f);
            q.b4[2] = f2i8(zr[p4.z], 32.0f);
            q.b4[3] = f2i8(zr[p4.w], 32.0f);
            *(uint32_t*)&zp[(size_t)b * D + i0] = q.u;
        }
    }
}

// ---------------------------------------------------------------------------
// GEMM1 (int8, K=64/MFMA, BK=128, 32KB LDS):
//   h = fp8(relu(acc/32768 + b1)) + fused exact partial log-det (f32 h).
// (unchanged from R17 — validated)
// ---------------------------------------------------------------------------
__global__ __launch_bounds__(256) void gemm1_k(
    const int8_t* __restrict__ A, const int8_t* __restrict__ Bt,
    const float* __restrict__ bias, const float* __restrict__ ws2p,
    uint8_t* __restrict__ Cout, float* __restrict__ ld,
    int M, int N, int K) {
    __shared__ __align__(16) int8_t Alds[128 * 128];
    __shared__ __align__(16) int8_t Blds[128 * 128];
    __shared__ float pdl[128];

    const int id   = blockIdx.x;
    const int xcd  = id & 7, s = id >> 3;     // s in [0,128)
    const int mb   = s & 31;
    const int nb   = xcd * 4 + (s >> 5);
    const int m0   = mb * 128;
    const int n0   = nb * 128;

    const int tid  = threadIdx.x;
    const int lane = tid & 63;
    const int w    = tid >> 6;
    const int wm   = (w & 1) * 64;
    const int wn   = (w >> 1) * 64;
    const int quad = lane >> 4;
    const int l16  = lane & 15;

    i32x4 acc[4][4];
#pragma unroll
    for (int i = 0; i < 4; i++)
#pragma unroll
        for (int j = 0; j < 4; j++) acc[i][j] = (i32x4)0;

    const int8_t* Ag[4];
    const int8_t* Bg[4];
    int8_t *Al[4], *Bl[4];
#pragma unroll
    for (int k = 0; k < 4; k++) {
        const int c  = tid + k * 256;
        const int so = ((c & 7) ^ ((c >> 3) & 7)) * 16;  // bytes
        Ag[k] = A + (size_t)(m0 + (c >> 3)) * K + so;
        Bg[k] = Bt + (size_t)(n0 + (c >> 3)) * K + so;
        Al[k] = &Alds[c * 16];
        Bl[k] = &Blds[c * 16];
    }

    const int sw   = l16 & 7;
    const int arow = (wm + l16) * 128;
    const int brow = (wn + l16) * 128;

    for (int kt = 0; kt < K; kt += 128) {
        __syncthreads();
#pragma unroll
        for (int k = 0; k < 4; k++) {
            GLD16(Ag[k] + kt, Al[k]);
            GLD16(Bg[k] + kt, Bl[k]);
        }
        __syncthreads();

#pragma unroll
        for (int kh = 0; kh < 2; kh++) {
            const int pc = ((kh * 4 + quad) ^ sw) * 16;
            i32x4 af[4], bfr[4];
#pragma unroll
            for (int mi = 0; mi < 4; mi++)
                af[mi] = *(const i32x4*)&Alds[arow + mi * 16 * 128 + pc];
#pragma unroll
            for (int ni = 0; ni < 4; ni++)
                bfr[ni] = *(const i32x4*)&Blds[brow + ni * 16 * 128 + pc];
#pragma unroll
            for (int mi = 0; mi < 4; mi++)
#pragma unroll
                for (int ni = 0; ni < 4; ni++)
                    acc[mi][ni] = __builtin_amdgcn_mfma_i32_16x16x64_i8(
                        af[mi], bfr[ni], acc[mi][ni], 0, 0, 0);
        }
    }

    // epilogue: C/D layout col = lane&15, row = quad*4 + reg;  h = acc/32768+b
    const float inv = 1.0f / 32768.0f;
    float bv[4], wv[4];
#pragma unroll
    for (int ni = 0; ni < 4; ni++) {
        const int col = n0 + wn + ni * 16 + l16;
        bv[ni] = bias[col];
        float sv = 0.0f;
#pragma unroll
        for (int cb = 0; cb < 16; cb++) sv += ws2p[(size_t)cb * N + col];
        wv[ni] = sv;
    }
    float pd[4][4];
#pragma unroll
    for (int mi = 0; mi < 4; mi++)
#pragma unroll
        for (int r = 0; r < 4; r++) pd[mi][r] = 0.0f;

#pragma unroll
    for (int mi = 0; mi < 4; mi++) {
        const int row = m0 + wm + mi * 16 + quad * 4;
#pragma unroll
        for (int ni = 0; ni < 4; ni++) {
            const int col = n0 + wn + ni * 16 + l16;
#pragma unroll
            for (int r = 0; r < 4; r++) {
                float v = fmaxf((float)acc[mi][ni][r] * inv + bv[ni], 0.0f);
                pd[mi][r] += v * wv[ni];
                Cout[(size_t)(row + r) * N + col] = f2fp8(v);
            }
        }
    }

#pragma unroll
    for (int off = 1; off < 16; off <<= 1)
#pragma unroll
        for (int mi = 0; mi < 4; mi++)
#pragma unroll
            for (int r = 0; r < 4; r++)
                pd[mi][r] += __shfl_xor(pd[mi][r], off, 16);

    __syncthreads();
    if ((w >> 1) == 0 && l16 == 0)
#pragma unroll
        for (int mi = 0; mi < 4; mi++)
#pragma unroll
            for (int r = 0; r < 4; r++)
                pdl[wm + mi * 16 + quad * 4 + r] = pd[mi][r];
    __syncthreads();
    if ((w >> 1) == 1 && l16 == 0)
#pragma unroll
        for (int mi = 0; mi < 4; mi++)
#pragma unroll
            for (int r = 0; r < 4; r++)
                pdl[wm + mi * 16 + quad * 4 + r] += pd[mi][r];
    __syncthreads();
    if (tid < 128) atomicAdd(&ld[m0 + tid], pdl[tid]);
}

// ---------------------------------------------------------------------------
// GEMM2 fused (MX fp8, K=128/MFMA, BK=128, ring-3 144KB LDS, 512 thr):
//   block = 256 rows x 64 col-pairs; per 48KB K-tile buffer: A = 256x128B
//   at [0,32K), B = 128x128B at [32K,48K) (B rows 0-63 = mu cols
//   [p0,p0+64), 64-127 = ls cols [D+p0,..)). 8 waves = 4M x 2P, wave =
//   64 rows x 32 pairs, 16 MFMA/K-step. Counted-vmcnt depth-2 prefetch
//   (see header). Epilogue: x = z*exp(ls)+mu, identical math to R18.
//   Grid (B/256)*(D/64pairs/..) = 16*16 = 256 = 1 block/CU; nb=id&15 ->
//   XCD = nb%8 pins 2 B-slices (1MB) per XCD L2.
// ---------------------------------------------------------------------------
__global__ __launch_bounds__(512) void gemm2f_k(
    const uint8_t* __restrict__ A, const uint8_t* __restrict__ Bt,
    const float* __restrict__ b2, const int* __restrict__ perm,
    const float* __restrict__ z, const float* __restrict__ ld,
    float* __restrict__ out, int B, int D, int K) {
    __shared__ __align__(16) uint8_t lds[3][49152];
    __shared__ float red[8];

    const int id   = blockIdx.x;
    const int nb   = id & 15;         // col-pair block [0,16)
    const int s    = id >> 4;         // m-block [0,16)
    const int m0   = s * 256;
    const int p0   = nb * 64;         // col-pair base

    const int tid  = threadIdx.x;
    const int lane = tid & 63;
    const int w    = tid >> 6;        // 0..7
    const int wm   = (w & 3) * 64;    // wave rows (4 M-groups)
    const int wp   = (w >> 2) * 32;   // wave col-pairs (2 P-groups)
    const int quad = lane >> 4;
    const int l16  = lane & 15;

    f32x4 acc[4][4];
#pragma unroll
    for (int i = 0; i < 4; i++)
#pragma unroll
        for (int j = 0; j < 4; j++) acc[i][j] = (f32x4)0.0f;

    // staging: 3072 chunks/K-tile (A 2048, B 1024); 6 chunks/thread
    const uint8_t* Gsrc[6];
    int ldst[6];
#pragma unroll
    for (int k = 0; k < 6; k++) {
        const int cid = tid + k * 512;
        const int r   = cid >> 3;
        const int so  = ((cid & 7) ^ (r & 7)) * 16;  // bytes
        if (r < 256) {
            Gsrc[k] = A + (size_t)(m0 + r) * K + so;
        } else {
            const int br = r - 256;
            const int g  = (br < 64) ? (p0 + br) : (D + p0 + (br - 64));
            Gsrc[k] = Bt + (size_t)g * K + so;
        }
        ldst[k] = cid * 16;
    }

#define STAGE2F(bi, kt)                                                      \
    _Pragma("unroll")                                                        \
    for (int k = 0; k < 6; k++) GLD16(Gsrc[k] + (kt), &lds[bi][ldst[k]]);

    const int sw   = l16 & 7;
    const int pc0  = ((quad * 2) ^ sw) * 16;
    const int pc1  = ((quad * 2 + 1) ^ sw) * 16;
    int arow[4], brow[4];
#pragma unroll
    for (int mi = 0; mi < 4; mi++) arow[mi] = (wm + mi * 16 + l16) * 128;
#pragma unroll
    for (int ni = 0; ni < 4; ni++)
        brow[ni] = 32768 + ((ni >> 1) * 64 + wp + (ni & 1) * 16 + l16) * 128;

    // prologue: tiles 0 and 1 in flight (12 loads/thread)
    STAGE2F(0, 0)
    STAGE2F(1, 128)

    const int NT = K / 128;   // 32
    for (int t = 0; t < NT; ++t) {
        if (t < NT - 1) {
            // oldest 6 loads (tile t) done; tiles t+1[,t+2] stay in flight
            asm volatile("s_waitcnt vmcnt(6)" ::: "memory");
        } else {
            asm volatile("s_waitcnt vmcnt(0)" ::: "memory");
        }
        __builtin_amdgcn_s_barrier();
        const int cur = t % 3;
        if (t + 2 < NT) {
            const int nx = (t + 2) % 3;
            STAGE2F(nx, (t + 2) * 128)
        }
        const uint8_t* buf = &lds[cur][0];
        union ABu { int4 h2[2]; i32x8 v; };
        i32x8 af[4], bfr[4];
#pragma unroll
        for (int mi = 0; mi < 4; mi++) {
            ABu tt;
            tt.h2[0] = *(const int4*)&buf[arow[mi] + pc0];
            tt.h2[1] = *(const int4*)&buf[arow[mi] + pc1];
            af[mi] = tt.v;
        }
#pragma unroll
        for (int ni = 0; ni < 4; ni++) {
            ABu tt;
            tt.h2[0] = *(const int4*)&buf[brow[ni] + pc0];
            tt.h2[1] = *(const int4*)&buf[brow[ni] + pc1];
            bfr[ni] = tt.v;
        }
        __builtin_amdgcn_s_setprio(1);
#pragma unroll
        for (int mi = 0; mi < 4; mi++)
#pragma unroll
            for (int ni = 0; ni < 4; ni++)
                acc[mi][ni] = MFMA_MX(af[mi], bfr[ni], acc[mi][ni]);
        __builtin_amdgcn_s_setprio(0);
    }

    // fused epilogue: mu = acc[mi][ci]/256 + b2[c]; ls = acc[mi][ci+2]/256
    //  + b2[D+c] (clamped); x[row][perm[c]] = z[row][perm[c]]*exp(ls)+mu.
    const float inv = 1.0f / 256.0f;
    float bmu[2], bls[2];
    int   pcv[2];
#pragma unroll
    for (int ci = 0; ci < 2; ci++) {
        const int gc = p0 + wp + ci * 16 + l16;
        bmu[ci] = b2[gc];
        bls[ci] = b2[D + gc];
        pcv[ci] = perm[gc];
    }
#pragma unroll
    for (int mi = 0; mi < 4; mi++) {
        const int row0 = m0 + wm + mi * 16 + quad * 4;
#pragma unroll
        for (int ci = 0; ci < 2; ci++) {
#pragma unroll
            for (int r = 0; r < 4; r++) {
                const size_t idx = (size_t)(row0 + r) * D + pcv[ci];
                const float mu = acc[mi][ci][r] * inv + bmu[ci];
                float ls = acc[mi][ci + 2][r] * inv + bls[ci];
                ls = fminf(fmaxf(ls, -30.0f), 30.0f);
                out[idx] = z[idx] * expf(ls) + mu;
            }
        }
    }

    // log_det: out[B*D + b] = ld[b] + sum(b2[D:2D))   (nb==0 blocks only)
    if (nb == 0) {
        float bs = 0.0f;
        for (int i = tid; i < D; i += 512) bs += b2[D + i];
#pragma unroll
        for (int o = 32; o > 0; o >>= 1) bs += __shfl_down(bs, o, 64);
        if ((tid & 63) == 0) red[tid >> 6] = bs;
        __syncthreads();
        if (tid < 256) {
            float rs = 0.0f;
#pragma unroll
            for (int k = 0; k < 8; k++) rs += red[k];
            out[(size_t)B * D + m0 + tid] = ld[m0 + tid] + rs;
        }
    }
}

// ---------------------------------------------------------------------------
extern "C" void kernel_launch(void* const* d_in, const int* in_sizes, int n_in,
                              void* d_out, int out_size, void* d_ws, size_t ws_size,
                              hipStream_t stream) {
    const float* z    = (const float*)d_in[0];
    const float* W1   = (const float*)d_in[1];
    const float* b1   = (const float*)d_in[2];
    const float* W2   = (const float*)d_in[3];
    const float* b2   = (const float*)d_in[4];
    const int*   perm = (const int*)d_in[5];
    float* out = (float*)d_out;
    char*  ws  = (char*)d_ws;

    const int D = in_sizes[5];          // 1024
    const int H = in_sizes[2];          // 4096
    const int B = in_sizes[0] / D;      // 4096

    const size_t off_h    = 0;                                  // B*H fp8 16MB
    const size_t off_W2mT = off_h    + (size_t)B * H;           // 2D*H fp8 8MB
    const size_t off_W1mT = off_W2mT + (size_t)2 * D * H;       // H*D i8  4MB
    const size_t off_zp   = off_W1mT + (size_t)H * D;           // B*D i8  4MB
    const size_t off_ws2  = off_zp   + (size_t)B * D;           // 16*H*4 256KB
    const size_t off_ld   = off_ws2  + (size_t)16 * H * 4;      // B*4

    uint8_t* h    = (uint8_t*)(ws + off_h);
    uint8_t* W2mT = (uint8_t*)(ws + off_W2mT);
    int8_t*  W1mT = (int8_t*)(ws + off_W1mT);
    int8_t*  zp   = (int8_t*)(ws + off_zp);
    float*   ws2p = (float*)(ws + off_ws2);
    float*   ld   = (float*)(ws + off_ld);

    // fused preprocessing: mt1 (+ ld zero) | mt2 (+ ws2 partials) | perm
    const int NB1 = (H / 64) * (D / 64);       // 1024
    const int NB2 = (2 * D / 64) * (H / 64);   // 2048
    const int NBP = B / 2;                     // 2048
    prep_k<<<NB1 + NB2 + NBP, 256, 0, stream>>>(
        W1, W1mT, W2, W2mT, ws2p, z, perm, zp, ld, D, H, B);

    // h = fp8(relu((zp @ W1m)/32768 + b1)) + fused ld partials [M=B,N=H,K=D]
    gemm1_k<<<(H / 128) * (B / 128), 256, 0, stream>>>(
        zp, W1mT, b1, ws2p, h, ld, B, H, D);

    // fused: x = z*exp(log_s)+mu scattered by perm; log_det from ld.
    //   [M=B rows x D col-pairs, K=H]  grid = 16 m-blocks x 16 pair-blocks
    gemm2f_k<<<(B / 256) * (D / 64), 512, 0, stream>>>(
        h, W2mT, b2, perm, z, ld, out, B, D, H);
}

// Round 5
// 193.504 us; speedup vs baseline: 1.0277x; 1.0277x over previous
//
#include <hip/hip_runtime.h>
#include <stdint.h>

// ---------------------------------------------------------------------------
// MADE flow layer, f32 I/O.
//   h  = relu(zp @ (W1*M1) + b1)     GEMM1: M=4096 N=4096 K=1024 (int8)
//   res= h @ (W2*M2) + b2            GEMM2: M=4096 N=2048 K=4096 (MX-fp8)
//   x[:, perm[i]] = zp*exp(log_s)+mu ; log_det exact via fused h.wsum2
//
// R20 (vs R19 FAIL @198.9us, gemm2f ring-3 = 55.2us): two moves.
// 1) REVERT gemm2f to R18's validated dbuf version (45.3us). R19 lesson =
//    m196: coarse 1-barrier counted ring at 1 block/CU loses the
//    inter-block TLP that the 2-blocks/CU dbuf structure relies on.
// 2) gemm1 -> mfma_i32_32x32x32_i8 (65536 FLOP/instr, 2x the 16x16x64).
//    gemm1 executed 1.05M MFMA instrs (same count as R0's 45.8us gemm2;
//    these structures are instruction-rate-bound ~27cy/instr). Halving
//    instruction count at identical staging/barriers/numerics (exact i32
//    accumulate) predicts gemm1 ~40 -> ~25us. A/B frag: row=lane&31,
//    k-chunk=kq*2+(lane>>5) (one b128, same XOR swizzle family). C/D:
//    col=lane&31, row=(r&3)+8*(r>>2)+4*(lane>>5) (HW-verified m74/m101).
// prep_k untouched (validated).
// ---------------------------------------------------------------------------

typedef float   f32x4  __attribute__((ext_vector_type(4)));
typedef int     i32x4  __attribute__((ext_vector_type(4)));
typedef int     i32x8  __attribute__((ext_vector_type(8)));
typedef int     i32x16 __attribute__((ext_vector_type(16)));

__device__ __forceinline__ uint8_t f2fp8(float f) {
    int p = __builtin_amdgcn_cvt_pk_fp8_f32(f, 0.0f, 0, false);
    return (uint8_t)(p & 0xff);
}
__device__ __forceinline__ int8_t f2i8(float v, float s) {
    float q = rintf(v * s);
    q = fminf(fmaxf(q, -127.0f), 127.0f);
    return (int8_t)q;
}

#define GLD16(g, l)                                                          \
    __builtin_amdgcn_global_load_lds(                                        \
        (const __attribute__((address_space(1))) uint32_t*)(g),              \
        (__attribute__((address_space(3))) uint32_t*)(l), 16, 0, 0)

#define MFMA_MX(a, b, c)                                                     \
    __builtin_amdgcn_mfma_scale_f32_16x16x128_f8f6f4(                        \
        (a), (b), (c), 0, 0, 0, 0x7F7F7F7F, 0, 0x7F7F7F7F)

// ---------------------------------------------------------------------------
// prep_k: fused preprocessing, block-role partitioned (unchanged from R17).
// ---------------------------------------------------------------------------
__global__ __launch_bounds__(256) void prep_k(
    const float* __restrict__ W1, int8_t* __restrict__ W1mT,
    const float* __restrict__ W2, uint8_t* __restrict__ W2mT,
    float* __restrict__ ws2p,
    const float* __restrict__ z, const int* __restrict__ perm,
    int8_t* __restrict__ zp, float* __restrict__ ld,
    int D, int H, int B) {
    const int bx  = blockIdx.x;
    const int tid = threadIdx.x;
    const int NB1 = (H / 64) * (D / 64);          // 1024
    const int NB2 = (2 * D / 64) * (H / 64);      // 2048

    if (bx < NB1) {
        // ---- mt1: masked transpose W1 -> int8 ----
        __shared__ int8_t t[64][68];
        const int c0 = (bx % (H / 64)) * 64;      // col in [0,H)
        const int r0 = (bx / (H / 64)) * 64;      // row in [0,D)
        const int tx = tid & 63, ty = tid >> 6;

        const int fid = bx * 256 + tid;
        if (fid < B) ld[fid] = 0.0f;

        for (int rr = ty; rr < 64; rr += 4) {
            const int r = r0 + rr, c = c0 + tx;
            float v = W1[(size_t)r * H + c];
            t[rr][tx] = ((c % (D - 1)) >= r) ? f2i8(v, 1024.0f) : (int8_t)0;
        }
        __syncthreads();
#pragma unroll
        for (int pass = 0; pass < 2; pass++) {
            const int cc = pass * 32 + (tid >> 3);
            const int j0 = (tid & 7) * 8;
            union { int8_t b[8]; uint64_t q; } v;
#pragma unroll
            for (int j = 0; j < 8; j++) v.b[j] = t[j0 + j][cc];
            *(uint64_t*)&W1mT[(size_t)(c0 + cc) * D + r0 + j0] = v.q;
        }
    } else if (bx < NB1 + NB2) {
        // ---- mt2: masked transpose W2 -> fp8 + ws2 partial row-sums ----
        __shared__ uint8_t t[64][68];
        const int idx = bx - NB1;
        const int c0 = (idx % (2 * D / 64)) * 64; // col in [0,2D)
        const int r0 = (idx / (2 * D / 64)) * 64; // row in [0,H)
        const int tx = tid & 63, ty = tid >> 6;
        const bool second = (c0 >= D);
        const int cb = (c0 - D) >> 6;             // partial slot [0,16)

        for (int rr = ty; rr < 64; rr += 4) {
            const int r = r0 + rr, c = c0 + tx;
            float v = W2[(size_t)r * 2 * D + c];
            bool keep = ((c % D) > (r % (D - 1)));
            t[rr][tx] = keep ? f2fp8(v * 256.0f) : (uint8_t)0;
            if (second) {
                float s = keep ? v : 0.0f;
#pragma unroll
                for (int o = 32; o > 0; o >>= 1) s += __shfl_down(s, o, 64);
                if (tx == 0) ws2p[(size_t)cb * H + r] = s;
            }
        }
        __syncthreads();
#pragma unroll
        for (int pass = 0; pass < 2; pass++) {
            const int cc = pass * 32 + (tid >> 3);
            const int j0 = (tid & 7) * 8;
            union { uint8_t b[8]; uint64_t q; } v;
#pragma unroll
            for (int j = 0; j < 8; j++) v.b[j] = t[j0 + j][cc];
            *(uint64_t*)&W2mT[(size_t)(c0 + cc) * H + r0 + j0] = v.q;
        }
    } else {
        // ---- perm+quant: 2 rows/block, 4 elems/thread/row ----
        const int bp = bx - NB1 - NB2;
        const int i0 = tid * 4;                   // D = 1024 = 256*4
        const int4 p4 = *(const int4*)(perm + i0);
#pragma unroll
        for (int rr = 0; rr < 2; rr++) {
            const int b = bp * 2 + rr;
            const float* zr = z + (size_t)b * D;
            union { int8_t b4[4]; uint32_t u; } q;
            q.b4[0] = f2i8(zr[p4.x], 32.0f);
            q.b4[1] = f2i8(zr[p4.y], 32.0f);
            q.b4[2] = f2i8(zr[p4.z], 32.0f);
            q.b4[3] = f2i8(zr[p4.w], 32.0f);
            *(uint32_t*)&zp[(size_t)b * D + i0] = q.u;
        }
    }
}

// ---------------------------------------------------------------------------
// GEMM1 (int8 32x32x32, BK=128, 32KB LDS, 2-barrier structure):
//   h = fp8(relu(acc/32768 + b1)) + fused exact partial log-det (f32 h).
// Staging/swizzle byte-identical to the validated structure. Inner loop:
// 4 k-quarters x acc[2][2] of 32x32 MFMA (16 instr @65536 FLOP = 2x R17's
// FLOP/instr at the same ds_read count). Epilogue uses the 32x32 C/D map.
// ---------------------------------------------------------------------------
__global__ __launch_bounds__(256) void gemm1_k(
    const int8_t* __restrict__ A, const int8_t* __restrict__ Bt,
    const float* __restrict__ bias, const float* __restrict__ ws2p,
    uint8_t* __restrict__ Cout, float* __restrict__ ld,
    int M, int N, int K) {
    __shared__ __align__(16) int8_t Alds[128 * 128];
    __shared__ __align__(16) int8_t Blds[128 * 128];
    __shared__ float pdl[128];

    const int id   = blockIdx.x;
    const int xcd  = id & 7, s = id >> 3;     // s in [0,128)
    const int mb   = s & 31;
    const int nb   = xcd * 4 + (s >> 5);
    const int m0   = mb * 128;
    const int n0   = nb * 128;

    const int tid  = threadIdx.x;
    const int lane = tid & 63;
    const int w    = tid >> 6;
    const int wm   = (w & 1) * 64;
    const int wn   = (w >> 1) * 64;
    const int l32  = lane & 31;
    const int h32  = lane >> 5;               // 0/1: k-chunk half

    i32x16 acc[2][2];
#pragma unroll
    for (int i = 0; i < 2; i++)
#pragma unroll
        for (int j = 0; j < 2; j++) acc[i][j] = (i32x16)0;

    const int8_t* Ag[4];
    const int8_t* Bg[4];
    int8_t *Al[4], *Bl[4];
#pragma unroll
    for (int k = 0; k < 4; k++) {
        const int c  = tid + k * 256;
        const int so = ((c & 7) ^ ((c >> 3) & 7)) * 16;  // bytes
        Ag[k] = A + (size_t)(m0 + (c >> 3)) * K + so;
        Bg[k] = Bt + (size_t)(n0 + (c >> 3)) * K + so;
        Al[k] = &Alds[c * 16];
        Bl[k] = &Blds[c * 16];
    }

    const int sw = l32 & 7;   // row&7 (wm, mi*32 are multiples of 8)

    for (int kt = 0; kt < K; kt += 128) {
        __syncthreads();
#pragma unroll
        for (int k = 0; k < 4; k++) {
            GLD16(Ag[k] + kt, Al[k]);
            GLD16(Bg[k] + kt, Bl[k]);
        }
        __syncthreads();

#pragma unroll
        for (int kq = 0; kq < 4; kq++) {
            const int pc = ((kq * 2 + h32) ^ sw) * 16;
            i32x4 af[2], bfr[2];
#pragma unroll
            for (int mi = 0; mi < 2; mi++)
                af[mi] = *(const i32x4*)&Alds[(wm + mi * 32 + l32) * 128 + pc];
#pragma unroll
            for (int ni = 0; ni < 2; ni++)
                bfr[ni] = *(const i32x4*)&Blds[(wn + ni * 32 + l32) * 128 + pc];
#pragma unroll
            for (int mi = 0; mi < 2; mi++)
#pragma unroll
                for (int ni = 0; ni < 2; ni++)
                    acc[mi][ni] = __builtin_amdgcn_mfma_i32_32x32x32_i8(
                        af[mi], bfr[ni], acc[mi][ni], 0, 0, 0);
        }
    }

    // epilogue: 32x32 C/D layout col = lane&31, row = (r&3)+8*(r>>2)+4*h32
    const float inv = 1.0f / 32768.0f;
    float bv[2], wv[2];
#pragma unroll
    for (int ni = 0; ni < 2; ni++) {
        const int col = n0 + wn + ni * 32 + l32;
        bv[ni] = bias[col];
        float sv = 0.0f;
#pragma unroll
        for (int cb = 0; cb < 16; cb++) sv += ws2p[(size_t)cb * N + col];
        wv[ni] = sv;
    }
    float pd[2][16];
#pragma unroll
    for (int mi = 0; mi < 2; mi++)
#pragma unroll
        for (int r = 0; r < 16; r++) pd[mi][r] = 0.0f;

#pragma unroll
    for (int mi = 0; mi < 2; mi++) {
#pragma unroll
        for (int ni = 0; ni < 2; ni++) {
            const int col = n0 + wn + ni * 32 + l32;
#pragma unroll
            for (int r = 0; r < 16; r++) {
                const int row =
                    m0 + wm + mi * 32 + (r & 3) + 8 * (r >> 2) + 4 * h32;
                float v = fmaxf((float)acc[mi][ni][r] * inv + bv[ni], 0.0f);
                pd[mi][r] += v * wv[ni];
                Cout[(size_t)row * N + col] = f2fp8(v);
            }
        }
    }

    // reduce pd over the 32 col-lanes (lanes sharing h32 hold same rows)
#pragma unroll
    for (int off = 1; off < 32; off <<= 1)
#pragma unroll
        for (int mi = 0; mi < 2; mi++)
#pragma unroll
            for (int r = 0; r < 16; r++)
                pd[mi][r] += __shfl_xor(pd[mi][r], off, 32);

    __syncthreads();
    if ((w >> 1) == 0 && l32 == 0)
#pragma unroll
        for (int mi = 0; mi < 2; mi++)
#pragma unroll
            for (int r = 0; r < 16; r++)
                pdl[wm + mi * 32 + (r & 3) + 8 * (r >> 2) + 4 * h32] = pd[mi][r];
    __syncthreads();
    if ((w >> 1) == 1 && l32 == 0)
#pragma unroll
        for (int mi = 0; mi < 2; mi++)
#pragma unroll
            for (int r = 0; r < 16; r++)
                pdl[wm + mi * 32 + (r & 3) + 8 * (r >> 2) + 4 * h32] += pd[mi][r];
    __syncthreads();
    if (tid < 128) atomicAdd(&ld[m0 + tid], pdl[tid]);
}

// ---------------------------------------------------------------------------
// GEMM2 fused (MX fp8, K=128/MFMA, BK=128, 64KB LDS double-buffered):
//   block = 128 rows x 64 col-pairs; B-tile rows 0-63 = mu cols [p0,p0+64),
//   rows 64-127 = ls cols [D+p0,D+p0+64). Each thread holds matching mu
//   (acc ni<2) and log_s (acc ni>=2) for the same column -> epilogue
//   computes x = z*exp(ls)+mu directly. nb==0 blocks also emit log_det.
//   2-phase prefetch, one __syncthreads per K-step.
//   (REVERTED to R18 — validated 45.3us)
// ---------------------------------------------------------------------------
__global__ __launch_bounds__(256) void gemm2f_k(
    const uint8_t* __restrict__ A, const uint8_t* __restrict__ Bt,
    const float* __restrict__ b2, const int* __restrict__ perm,
    const float* __restrict__ z, const float* __restrict__ ld,
    float* __restrict__ out, int B, int D, int K) {
    __shared__ __align__(16) uint8_t Alds[2][128 * 128];
    __shared__ __align__(16) uint8_t Blds[2][128 * 128];
    __shared__ float red[4];

    const int id   = blockIdx.x;
    const int nb   = id & 15;         // col-pair block [0,16)
    const int s    = id >> 4;         // m-block [0,32)
    const int m0   = s * 128;
    const int p0   = nb * 64;         // col-pair base

    const int tid  = threadIdx.x;
    const int lane = tid & 63;
    const int w    = tid >> 6;
    const int wm   = (w & 1) * 64;    // wave rows
    const int wp   = (w >> 1) * 32;   // wave col-pairs
    const int quad = lane >> 4;
    const int l16  = lane & 15;

    f32x4 acc[4][4];
#pragma unroll
    for (int i = 0; i < 4; i++)
#pragma unroll
        for (int j = 0; j < 4; j++) acc[i][j] = (f32x4)0.0f;

    // staging: A = 128 rows x 128B, B = 128 rows x 128B (4 chunks/thread ea)
    const uint8_t* Ag[4];
    const uint8_t* Bg[4];
    int ldso[4];
#pragma unroll
    for (int k = 0; k < 4; k++) {
        const int c  = tid + k * 256;
        const int r  = c >> 3;
        const int so = ((c & 7) ^ (r & 7)) * 16;  // bytes
        Ag[k] = A + (size_t)(m0 + r) * K + so;
        const int g = (r < 64) ? (p0 + r) : (D + p0 + (r - 64));
        Bg[k] = Bt + (size_t)g * K + so;
        ldso[k] = c * 16;
    }

    const int sw   = l16 & 7;
    const int pc0  = ((quad * 2) ^ sw) * 16;
    const int pc1  = ((quad * 2 + 1) ^ sw) * 16;

    // prologue: stage K-tile 0 into buf 0
#pragma unroll
    for (int k = 0; k < 4; k++) {
        GLD16(Ag[k], &Alds[0][ldso[k]]);
        GLD16(Bg[k], &Blds[0][ldso[k]]);
    }
    __syncthreads();

    int cur = 0;
    for (int kt = 0; kt < K; kt += 128) {
        const int nxt = cur ^ 1;
        if (kt + 128 < K) {
#pragma unroll
            for (int k = 0; k < 4; k++) {
                GLD16(Ag[k] + kt + 128, &Alds[nxt][ldso[k]]);
                GLD16(Bg[k] + kt + 128, &Blds[nxt][ldso[k]]);
            }
        }
        union ABu { int4 h2[2]; i32x8 v; };
        i32x8 af[4], bfr[4];
#pragma unroll
        for (int mi = 0; mi < 4; mi++) {
            ABu t;
            const int ar = (wm + mi * 16 + l16) * 128;
            t.h2[0] = *(const int4*)&Alds[cur][ar + pc0];
            t.h2[1] = *(const int4*)&Alds[cur][ar + pc1];
            af[mi] = t.v;
        }
#pragma unroll
        for (int ni = 0; ni < 4; ni++) {
            ABu t;
            const int br = ((ni >> 1) * 64 + wp + (ni & 1) * 16 + l16) * 128;
            t.h2[0] = *(const int4*)&Blds[cur][br + pc0];
            t.h2[1] = *(const int4*)&Blds[cur][br + pc1];
            bfr[ni] = t.v;
        }
#pragma unroll
        for (int mi = 0; mi < 4; mi++)
#pragma unroll
            for (int ni = 0; ni < 4; ni++)
                acc[mi][ni] = MFMA_MX(af[mi], bfr[ni], acc[mi][ni]);
        __syncthreads();   // drains prefetch (vmcnt) + covers LDS reuse
        cur = nxt;
    }

    // fused epilogue: mu = acc[mi][ci]/256 + b2[c]; ls = acc[mi][ci+2]/256
    //  + b2[D+c] (clamped); x[row][perm[c]] = z[row][perm[c]]*exp(ls)+mu.
    const float inv = 1.0f / 256.0f;
    float bmu[2], bls[2];
    int   pcv[2];
#pragma unroll
    for (int ci = 0; ci < 2; ci++) {
        const int gc = p0 + wp + ci * 16 + l16;
        bmu[ci] = b2[gc];
        bls[ci] = b2[D + gc];
        pcv[ci] = perm[gc];
    }
#pragma unroll
    for (int mi = 0; mi < 4; mi++) {
        const int row0 = m0 + wm + mi * 16 + quad * 4;
#pragma unroll
        for (int ci = 0; ci < 2; ci++) {
#pragma unroll
            for (int r = 0; r < 4; r++) {
                const size_t idx = (size_t)(row0 + r) * D + pcv[ci];
                const float mu = acc[mi][ci][r] * inv + bmu[ci];
                float ls = acc[mi][ci + 2][r] * inv + bls[ci];
                ls = fminf(fmaxf(ls, -30.0f), 30.0f);
                out[idx] = z[idx] * expf(ls) + mu;
            }
        }
    }

    // log_det: out[B*D + b] = ld[b] + sum(b2[D:2D))   (nb==0 blocks only)
    if (nb == 0) {
        float bs = 0.0f;
        for (int i = tid; i < D; i += 256) bs += b2[D + i];
#pragma unroll
        for (int o = 32; o > 0; o >>= 1) bs += __shfl_down(bs, o, 64);
        if ((tid & 63) == 0) red[tid >> 6] = bs;
        __syncthreads();
        if (tid < 128)
            out[(size_t)B * D + m0 + tid] =
                ld[m0 + tid] + red[0] + red[1] + red[2] + red[3];
    }
}

// ---------------------------------------------------------------------------
extern "C" void kernel_launch(void* const* d_in, const int* in_sizes, int n_in,
                              void* d_out, int out_size, void* d_ws, size_t ws_size,
                              hipStream_t stream) {
    const float* z    = (const float*)d_in[0];
    const float* W1   = (const float*)d_in[1];
    const float* b1   = (const float*)d_in[2];
    const float* W2   = (const float*)d_in[3];
    const float* b2   = (const float*)d_in[4];
    const int*   perm = (const int*)d_in[5];
    float* out = (float*)d_out;
    char*  ws  = (char*)d_ws;

    const int D = in_sizes[5];          // 1024
    const int H = in_sizes[2];          // 4096
    const int B = in_sizes[0] / D;      // 4096

    const size_t off_h    = 0;                                  // B*H fp8 16MB
    const size_t off_W2mT = off_h    + (size_t)B * H;           // 2D*H fp8 8MB
    const size_t off_W1mT = off_W2mT + (size_t)2 * D * H;       // H*D i8  4MB
    const size_t off_zp   = off_W1mT + (size_t)H * D;           // B*D i8  4MB
    const size_t off_ws2  = off_zp   + (size_t)B * D;           // 16*H*4 256KB
    const size_t off_ld   = off_ws2  + (size_t)16 * H * 4;      // B*4

    uint8_t* h    = (uint8_t*)(ws + off_h);
    uint8_t* W2mT = (uint8_t*)(ws + off_W2mT);
    int8_t*  W1mT = (int8_t*)(ws + off_W1mT);
    int8_t*  zp   = (int8_t*)(ws + off_zp);
    float*   ws2p = (float*)(ws + off_ws2);
    float*   ld   = (float*)(ws + off_ld);

    // fused preprocessing: mt1 (+ ld zero) | mt2 (+ ws2 partials) | perm
    const int NB1 = (H / 64) * (D / 64);       // 1024
    const int NB2 = (2 * D / 64) * (H / 64);   // 2048
    const int NBP = B / 2;                     // 2048
    prep_k<<<NB1 + NB2 + NBP, 256, 0, stream>>>(
        W1, W1mT, W2, W2mT, ws2p, z, perm, zp, ld, D, H, B);

    // h = fp8(relu((zp @ W1m)/32768 + b1)) + fused ld partials [M=B,N=H,K=D]
    gemm1_k<<<(H / 128) * (B / 128), 256, 0, stream>>>(
        zp, W1mT, b1, ws2p, h, ld, B, H, D);

    // fused: x = z*exp(log_s)+mu scattered by perm; log_det from ld.
    //   [M=B rows x D col-pairs, K=H]  grid = (D/64)*(B/128) = 512
    gemm2f_k<<<(D / 64) * (B / 128), 256, 0, stream>>>(
        h, W2mT, b2, perm, z, ld, out, B, D, H);
}

// Round 6
// 178.427 us; speedup vs baseline: 1.1146x; 1.0845x over previous
//
#include <hip/hip_runtime.h>
#include <stdint.h>

// ---------------------------------------------------------------------------
// MADE flow layer, f32 I/O.
//   h  = relu(zp @ (W1*M1) + b1)     GEMM1: M=4096 N=4096 K=1024 (int8)
//   res= h @ (W2*M2) + b2            GEMM2: M=4096 N=2048 K=4096 (MX-fp8)
//   x[:, perm[i]] = zp*exp(log_s)+mu ; log_det exact via fused h.wsum2
//
// R21 (vs R20 @193.5us): recovery + prep vectorization.
// R20 post-mortem: 32x32x32 gemm1 was -4us vs 16x16x64 (same matrix-pipe
// cycles, 2x ds_read_b128); wall accounting shows ~70us of harness
// restore dispatches (Dispatch_Id stride 44/iter) we cannot touch —
// controllable budget ~125us. This round:
//  1) gemm1 REVERTED to R18/R3-validated 16x16x64 (known ~25-30us).
//  2) prep mt1/mt2 roles vectorized: float4 loads (16B/lane, 4 row-iters
//     vs 16 scalar), packed 4B LDS stores, 16-lane-group shfl reduce for
//     ws2 partials. ~80MB traffic -> push toward BW roofline.
//  3) gemm2f byte-identical to R18 (validated 45.3us).
// ---------------------------------------------------------------------------

typedef float   f32x4  __attribute__((ext_vector_type(4)));
typedef int     i32x4  __attribute__((ext_vector_type(4)));
typedef int     i32x8  __attribute__((ext_vector_type(8)));

__device__ __forceinline__ uint8_t f2fp8(float f) {
    int p = __builtin_amdgcn_cvt_pk_fp8_f32(f, 0.0f, 0, false);
    return (uint8_t)(p & 0xff);
}
__device__ __forceinline__ int8_t f2i8(float v, float s) {
    float q = rintf(v * s);
    q = fminf(fmaxf(q, -127.0f), 127.0f);
    return (int8_t)q;
}

#define GLD16(g, l)                                                          \
    __builtin_amdgcn_global_load_lds(                                        \
        (const __attribute__((address_space(1))) uint32_t*)(g),              \
        (__attribute__((address_space(3))) uint32_t*)(l), 16, 0, 0)

#define MFMA_MX(a, b, c)                                                     \
    __builtin_amdgcn_mfma_scale_f32_16x16x128_f8f6f4(                        \
        (a), (b), (c), 0, 0, 0, 0x7F7F7F7F, 0, 0x7F7F7F7F)

// ---------------------------------------------------------------------------
// prep_k: fused preprocessing, block-role partitioned.
//   role A [0, NB1):        mt1 — W1 -> W1mT int8 x1024, masked transpose.
//   role B [NB1, NB1+NB2):  mt2 — W2 -> W2mT fp8 x256, masked transpose,
//                           second-half blocks write ws2p partials.
//   role C [rest):          perm — zp[b][i] = i8(32 * z[b][perm[i]]).
// R21: roles A/B load float4 (16B/lane), pack 4B into LDS; ws2 row-sum
// via 16-lane-group shfl (threads tid = (rr%16)*16 + q hold row rr).
// ---------------------------------------------------------------------------
__global__ __launch_bounds__(256) void prep_k(
    const float* __restrict__ W1, int8_t* __restrict__ W1mT,
    const float* __restrict__ W2, uint8_t* __restrict__ W2mT,
    float* __restrict__ ws2p,
    const float* __restrict__ z, const int* __restrict__ perm,
    int8_t* __restrict__ zp, float* __restrict__ ld,
    int D, int H, int B) {
    const int bx  = blockIdx.x;
    const int tid = threadIdx.x;
    const int NB1 = (H / 64) * (D / 64);          // 1024
    const int NB2 = (2 * D / 64) * (H / 64);      // 2048

    if (bx < NB1) {
        // ---- mt1: masked transpose W1 -> int8 (float4 loads) ----
        __shared__ int8_t t[64][68];
        const int c0 = (bx % (H / 64)) * 64;      // col in [0,H)
        const int r0 = (bx / (H / 64)) * 64;      // row in [0,D)
        const int q  = tid & 15;                  // float4-col group
        const int r  = tid >> 4;                  // row phase 0..15

        const int fid = bx * 256 + tid;
        if (fid < B) ld[fid] = 0.0f;

#pragma unroll
        for (int rr0 = 0; rr0 < 64; rr0 += 16) {
            const int rr  = rr0 + r;
            const int row = r0 + rr;
            const float4 v4 =
                *(const float4*)&W1[(size_t)row * H + c0 + q * 4];
            const float vv[4] = {v4.x, v4.y, v4.z, v4.w};
            union { int8_t b4[4]; uint32_t u; } pk;
#pragma unroll
            for (int j = 0; j < 4; j++) {
                const int c = c0 + q * 4 + j;
                pk.b4[j] = ((c % (D - 1)) >= row) ? f2i8(vv[j], 1024.0f)
                                                  : (int8_t)0;
            }
            *(uint32_t*)&t[rr][q * 4] = pk.u;
        }
        __syncthreads();
#pragma unroll
        for (int pass = 0; pass < 2; pass++) {
            const int cc = pass * 32 + (tid >> 3);
            const int j0 = (tid & 7) * 8;
            union { int8_t b[8]; uint64_t qq; } v;
#pragma unroll
            for (int j = 0; j < 8; j++) v.b[j] = t[j0 + j][cc];
            *(uint64_t*)&W1mT[(size_t)(c0 + cc) * D + r0 + j0] = v.qq;
        }
    } else if (bx < NB1 + NB2) {
        // ---- mt2: masked transpose W2 -> fp8 + ws2 partials (float4) ----
        __shared__ uint8_t t[64][68];
        const int idx = bx - NB1;
        const int c0 = (idx % (2 * D / 64)) * 64; // col in [0,2D)
        const int r0 = (idx / (2 * D / 64)) * 64; // row in [0,H)
        const int q  = tid & 15;
        const int r  = tid >> 4;
        const bool second = (c0 >= D);
        const int cb = (c0 - D) >> 6;             // partial slot [0,16)

#pragma unroll
        for (int rr0 = 0; rr0 < 64; rr0 += 16) {
            const int rr  = rr0 + r;
            const int row = r0 + rr;
            const float4 v4 =
                *(const float4*)&W2[(size_t)row * 2 * D + c0 + q * 4];
            const float vv[4] = {v4.x, v4.y, v4.z, v4.w};
            union { uint8_t b4[4]; uint32_t u; } pk;
            float s = 0.0f;
#pragma unroll
            for (int j = 0; j < 4; j++) {
                const int c = c0 + q * 4 + j;
                const bool keep = ((c % D) > (row % (D - 1)));
                pk.b4[j] = keep ? f2fp8(vv[j] * 256.0f) : (uint8_t)0;
                s += keep ? vv[j] : 0.0f;
            }
            *(uint32_t*)&t[rr][q * 4] = pk.u;
            if (second) {
                // threads holding row rr are 16 consecutive lanes
#pragma unroll
                for (int o = 8; o > 0; o >>= 1) s += __shfl_down(s, o, 16);
                if (q == 0) ws2p[(size_t)cb * H + row] = s;
            }
        }
        __syncthreads();
#pragma unroll
        for (int pass = 0; pass < 2; pass++) {
            const int cc = pass * 32 + (tid >> 3);
            const int j0 = (tid & 7) * 8;
            union { uint8_t b[8]; uint64_t qq; } v;
#pragma unroll
            for (int j = 0; j < 8; j++) v.b[j] = t[j0 + j][cc];
            *(uint64_t*)&W2mT[(size_t)(c0 + cc) * H + r0 + j0] = v.qq;
        }
    } else {
        // ---- perm+quant: 2 rows/block, 4 elems/thread/row ----
        const int bp = bx - NB1 - NB2;
        const int i0 = tid * 4;                   // D = 1024 = 256*4
        const int4 p4 = *(const int4*)(perm + i0);
#pragma unroll
        for (int rr = 0; rr < 2; rr++) {
            const int b = bp * 2 + rr;
            const float* zr = z + (size_t)b * D;
            union { int8_t b4[4]; uint32_t u; } q;
            q.b4[0] = f2i8(zr[p4.x], 32.0f);
            q.b4[1] = f2i8(zr[p4.y], 32.0f);
            q.b4[2] = f2i8(zr[p4.z], 32.0f);
            q.b4[3] = f2i8(zr[p4.w], 32.0f);
            *(uint32_t*)&zp[(size_t)b * D + i0] = q.u;
        }
    }
}

// ---------------------------------------------------------------------------
// GEMM1 (int8, K=64/MFMA, BK=128, 32KB LDS):
//   h = fp8(relu(acc/32768 + b1)) + fused exact partial log-det (f32 h).
// (REVERTED to R18/R3 16x16x64 — validated; R20's 32x32x32 was -4us)
// ---------------------------------------------------------------------------
__global__ __launch_bounds__(256) void gemm1_k(
    const int8_t* __restrict__ A, const int8_t* __restrict__ Bt,
    const float* __restrict__ bias, const float* __restrict__ ws2p,
    uint8_t* __restrict__ Cout, float* __restrict__ ld,
    int M, int N, int K) {
    __shared__ __align__(16) int8_t Alds[128 * 128];
    __shared__ __align__(16) int8_t Blds[128 * 128];
    __shared__ float pdl[128];

    const int id   = blockIdx.x;
    const int xcd  = id & 7, s = id >> 3;     // s in [0,128)
    const int mb   = s & 31;
    const int nb   = xcd * 4 + (s >> 5);
    const int m0   = mb * 128;
    const int n0   = nb * 128;

    const int tid  = threadIdx.x;
    const int lane = tid & 63;
    const int w    = tid >> 6;
    const int wm   = (w & 1) * 64;
    const int wn   = (w >> 1) * 64;
    const int quad = lane >> 4;
    const int l16  = lane & 15;

    i32x4 acc[4][4];
#pragma unroll
    for (int i = 0; i < 4; i++)
#pragma unroll
        for (int j = 0; j < 4; j++) acc[i][j] = (i32x4)0;

    const int8_t* Ag[4];
    const int8_t* Bg[4];
    int8_t *Al[4], *Bl[4];
#pragma unroll
    for (int k = 0; k < 4; k++) {
        const int c  = tid + k * 256;
        const int so = ((c & 7) ^ ((c >> 3) & 7)) * 16;  // bytes
        Ag[k] = A + (size_t)(m0 + (c >> 3)) * K + so;
        Bg[k] = Bt + (size_t)(n0 + (c >> 3)) * K + so;
        Al[k] = &Alds[c * 16];
        Bl[k] = &Blds[c * 16];
    }

    const int sw   = l16 & 7;
    const int arow = (wm + l16) * 128;
    const int brow = (wn + l16) * 128;

    for (int kt = 0; kt < K; kt += 128) {
        __syncthreads();
#pragma unroll
        for (int k = 0; k < 4; k++) {
            GLD16(Ag[k] + kt, Al[k]);
            GLD16(Bg[k] + kt, Bl[k]);
        }
        __syncthreads();

#pragma unroll
        for (int kh = 0; kh < 2; kh++) {
            const int pc = ((kh * 4 + quad) ^ sw) * 16;
            i32x4 af[4], bfr[4];
#pragma unroll
            for (int mi = 0; mi < 4; mi++)
                af[mi] = *(const i32x4*)&Alds[arow + mi * 16 * 128 + pc];
#pragma unroll
            for (int ni = 0; ni < 4; ni++)
                bfr[ni] = *(const i32x4*)&Blds[brow + ni * 16 * 128 + pc];
#pragma unroll
            for (int mi = 0; mi < 4; mi++)
#pragma unroll
                for (int ni = 0; ni < 4; ni++)
                    acc[mi][ni] = __builtin_amdgcn_mfma_i32_16x16x64_i8(
                        af[mi], bfr[ni], acc[mi][ni], 0, 0, 0);
        }
    }

    // epilogue: C/D layout col = lane&15, row = quad*4 + reg;  h = acc/32768+b
    const float inv = 1.0f / 32768.0f;
    float bv[4], wv[4];
#pragma unroll
    for (int ni = 0; ni < 4; ni++) {
        const int col = n0 + wn + ni * 16 + l16;
        bv[ni] = bias[col];
        float sv = 0.0f;
#pragma unroll
        for (int cb = 0; cb < 16; cb++) sv += ws2p[(size_t)cb * N + col];
        wv[ni] = sv;
    }
    float pd[4][4];
#pragma unroll
    for (int mi = 0; mi < 4; mi++)
#pragma unroll
        for (int r = 0; r < 4; r++) pd[mi][r] = 0.0f;

#pragma unroll
    for (int mi = 0; mi < 4; mi++) {
        const int row = m0 + wm + mi * 16 + quad * 4;
#pragma unroll
        for (int ni = 0; ni < 4; ni++) {
            const int col = n0 + wn + ni * 16 + l16;
#pragma unroll
            for (int r = 0; r < 4; r++) {
                float v = fmaxf((float)acc[mi][ni][r] * inv + bv[ni], 0.0f);
                pd[mi][r] += v * wv[ni];
                Cout[(size_t)(row + r) * N + col] = f2fp8(v);
            }
        }
    }

#pragma unroll
    for (int off = 1; off < 16; off <<= 1)
#pragma unroll
        for (int mi = 0; mi < 4; mi++)
#pragma unroll
            for (int r = 0; r < 4; r++)
                pd[mi][r] += __shfl_xor(pd[mi][r], off, 16);

    __syncthreads();
    if ((w >> 1) == 0 && l16 == 0)
#pragma unroll
        for (int mi = 0; mi < 4; mi++)
#pragma unroll
            for (int r = 0; r < 4; r++)
                pdl[wm + mi * 16 + quad * 4 + r] = pd[mi][r];
    __syncthreads();
    if ((w >> 1) == 1 && l16 == 0)
#pragma unroll
        for (int mi = 0; mi < 4; mi++)
#pragma unroll
            for (int r = 0; r < 4; r++)
                pdl[wm + mi * 16 + quad * 4 + r] += pd[mi][r];
    __syncthreads();
    if (tid < 128) atomicAdd(&ld[m0 + tid], pdl[tid]);
}

// ---------------------------------------------------------------------------
// GEMM2 fused (MX fp8, K=128/MFMA, BK=128, 64KB LDS double-buffered):
//   block = 128 rows x 64 col-pairs; B-tile rows 0-63 = mu cols [p0,p0+64),
//   rows 64-127 = ls cols [D+p0,D+p0+64). Each thread holds matching mu
//   (acc ni<2) and log_s (acc ni>=2) for the same column -> epilogue
//   computes x = z*exp(ls)+mu directly. nb==0 blocks also emit log_det.
//   2-phase prefetch, one __syncthreads per K-step.
//   (byte-identical to R18 — validated 45.3us)
// ---------------------------------------------------------------------------
__global__ __launch_bounds__(256) void gemm2f_k(
    const uint8_t* __restrict__ A, const uint8_t* __restrict__ Bt,
    const float* __restrict__ b2, const int* __restrict__ perm,
    const float* __restrict__ z, const float* __restrict__ ld,
    float* __restrict__ out, int B, int D, int K) {
    __shared__ __align__(16) uint8_t Alds[2][128 * 128];
    __shared__ __align__(16) uint8_t Blds[2][128 * 128];
    __shared__ float red[4];

    const int id   = blockIdx.x;
    const int nb   = id & 15;         // col-pair block [0,16)
    const int s    = id >> 4;         // m-block [0,32)
    const int m0   = s * 128;
    const int p0   = nb * 64;         // col-pair base

    const int tid  = threadIdx.x;
    const int lane = tid & 63;
    const int w    = tid >> 6;
    const int wm   = (w & 1) * 64;    // wave rows
    const int wp   = (w >> 1) * 32;   // wave col-pairs
    const int quad = lane >> 4;
    const int l16  = lane & 15;

    f32x4 acc[4][4];
#pragma unroll
    for (int i = 0; i < 4; i++)
#pragma unroll
        for (int j = 0; j < 4; j++) acc[i][j] = (f32x4)0.0f;

    // staging: A = 128 rows x 128B, B = 128 rows x 128B (4 chunks/thread ea)
    const uint8_t* Ag[4];
    const uint8_t* Bg[4];
    int ldso[4];
#pragma unroll
    for (int k = 0; k < 4; k++) {
        const int c  = tid + k * 256;
        const int r  = c >> 3;
        const int so = ((c & 7) ^ (r & 7)) * 16;  // bytes
        Ag[k] = A + (size_t)(m0 + r) * K + so;
        const int g = (r < 64) ? (p0 + r) : (D + p0 + (r - 64));
        Bg[k] = Bt + (size_t)g * K + so;
        ldso[k] = c * 16;
    }

    const int sw   = l16 & 7;
    const int pc0  = ((quad * 2) ^ sw) * 16;
    const int pc1  = ((quad * 2 + 1) ^ sw) * 16;

    // prologue: stage K-tile 0 into buf 0
#pragma unroll
    for (int k = 0; k < 4; k++) {
        GLD16(Ag[k], &Alds[0][ldso[k]]);
        GLD16(Bg[k], &Blds[0][ldso[k]]);
    }
    __syncthreads();

    int cur = 0;
    for (int kt = 0; kt < K; kt += 128) {
        const int nxt = cur ^ 1;
        if (kt + 128 < K) {
#pragma unroll
            for (int k = 0; k < 4; k++) {
                GLD16(Ag[k] + kt + 128, &Alds[nxt][ldso[k]]);
                GLD16(Bg[k] + kt + 128, &Blds[nxt][ldso[k]]);
            }
        }
        union ABu { int4 h2[2]; i32x8 v; };
        i32x8 af[4], bfr[4];
#pragma unroll
        for (int mi = 0; mi < 4; mi++) {
            ABu t;
            const int ar = (wm + mi * 16 + l16) * 128;
            t.h2[0] = *(const int4*)&Alds[cur][ar + pc0];
            t.h2[1] = *(const int4*)&Alds[cur][ar + pc1];
            af[mi] = t.v;
        }
#pragma unroll
        for (int ni = 0; ni < 4; ni++) {
            ABu t;
            const int br = ((ni >> 1) * 64 + wp + (ni & 1) * 16 + l16) * 128;
            t.h2[0] = *(const int4*)&Blds[cur][br + pc0];
            t.h2[1] = *(const int4*)&Blds[cur][br + pc1];
            bfr[ni] = t.v;
        }
#pragma unroll
        for (int mi = 0; mi < 4; mi++)
#pragma unroll
            for (int ni = 0; ni < 4; ni++)
                acc[mi][ni] = MFMA_MX(af[mi], bfr[ni], acc[mi][ni]);
        __syncthreads();   // drains prefetch (vmcnt) + covers LDS reuse
        cur = nxt;
    }

    // fused epilogue: mu = acc[mi][ci]/256 + b2[c]; ls = acc[mi][ci+2]/256
    //  + b2[D+c] (clamped); x[row][perm[c]] = z[row][perm[c]]*exp(ls)+mu.
    const float inv = 1.0f / 256.0f;
    float bmu[2], bls[2];
    int   pcv[2];
#pragma unroll
    for (int ci = 0; ci < 2; ci++) {
        const int gc = p0 + wp + ci * 16 + l16;
        bmu[ci] = b2[gc];
        bls[ci] = b2[D + gc];
        pcv[ci] = perm[gc];
    }
#pragma unroll
    for (int mi = 0; mi < 4; mi++) {
        const int row0 = m0 + wm + mi * 16 + quad * 4;
#pragma unroll
        for (int ci = 0; ci < 2; ci++) {
#pragma unroll
            for (int r = 0; r < 4; r++) {
                const size_t idx = (size_t)(row0 + r) * D + pcv[ci];
                const float mu = acc[mi][ci][r] * inv + bmu[ci];
                float ls = acc[mi][ci + 2][r] * inv + bls[ci];
                ls = fminf(fmaxf(ls, -30.0f), 30.0f);
                out[idx] = z[idx] * expf(ls) + mu;
            }
        }
    }

    // log_det: out[B*D + b] = ld[b] + sum(b2[D:2D))   (nb==0 blocks only)
    if (nb == 0) {
        float bs = 0.0f;
        for (int i = tid; i < D; i += 256) bs += b2[D + i];
#pragma unroll
        for (int o = 32; o > 0; o >>= 1) bs += __shfl_down(bs, o, 64);
        if ((tid & 63) == 0) red[tid >> 6] = bs;
        __syncthreads();
        if (tid < 128)
            out[(size_t)B * D + m0 + tid] =
                ld[m0 + tid] + red[0] + red[1] + red[2] + red[3];
    }
}

// ---------------------------------------------------------------------------
extern "C" void kernel_launch(void* const* d_in, const int* in_sizes, int n_in,
                              void* d_out, int out_size, void* d_ws, size_t ws_size,
                              hipStream_t stream) {
    const float* z    = (const float*)d_in[0];
    const float* W1   = (const float*)d_in[1];
    const float* b1   = (const float*)d_in[2];
    const float* W2   = (const float*)d_in[3];
    const float* b2   = (const float*)d_in[4];
    const int*   perm = (const int*)d_in[5];
    float* out = (float*)d_out;
    char*  ws  = (char*)d_ws;

    const int D = in_sizes[5];          // 1024
    const int H = in_sizes[2];          // 4096
    const int B = in_sizes[0] / D;      // 4096

    const size_t off_h    = 0;                                  // B*H fp8 16MB
    const size_t off_W2mT = off_h    + (size_t)B * H;           // 2D*H fp8 8MB
    const size_t off_W1mT = off_W2mT + (size_t)2 * D * H;       // H*D i8  4MB
    const size_t off_zp   = off_W1mT + (size_t)H * D;           // B*D i8  4MB
    const size_t off_ws2  = off_zp   + (size_t)B * D;           // 16*H*4 256KB
    const size_t off_ld   = off_ws2  + (size_t)16 * H * 4;      // B*4

    uint8_t* h    = (uint8_t*)(ws + off_h);
    uint8_t* W2mT = (uint8_t*)(ws + off_W2mT);
    int8_t*  W1mT = (int8_t*)(ws + off_W1mT);
    int8_t*  zp   = (int8_t*)(ws + off_zp);
    float*   ws2p = (float*)(ws + off_ws2);
    float*   ld   = (float*)(ws + off_ld);

    // fused preprocessing: mt1 (+ ld zero) | mt2 (+ ws2 partials) | perm
    const int NB1 = (H / 64) * (D / 64);       // 1024
    const int NB2 = (2 * D / 64) * (H / 64);   // 2048
    const int NBP = B / 2;                     // 2048
    prep_k<<<NB1 + NB2 + NBP, 256, 0, stream>>>(
        W1, W1mT, W2, W2mT, ws2p, z, perm, zp, ld, D, H, B);

    // h = fp8(relu((zp @ W1m)/32768 + b1)) + fused ld partials [M=B,N=H,K=D]
    gemm1_k<<<(H / 128) * (B / 128), 256, 0, stream>>>(
        zp, W1mT, b1, ws2p, h, ld, B, H, D);

    // fused: x = z*exp(log_s)+mu scattered by perm; log_det from ld.
    //   [M=B rows x D col-pairs, K=H]  grid = (D/64)*(B/128) = 512
    gemm2f_k<<<(D / 64) * (B / 128), 256, 0, stream>>>(
        h, W2mT, b2, perm, z, ld, out, B, D, H);
}

// Round 7
// 172.075 us; speedup vs baseline: 1.1557x; 1.0369x over previous
//
#include <hip/hip_runtime.h>
#include <stdint.h>

// ---------------------------------------------------------------------------
// MADE flow layer, f32 I/O.
//   h  = relu(zp @ (W1*M1) + b1)     GEMM1: M=4096 N=4096 K=1024 (int8)
//   res= h @ (W2*M2) + b2            GEMM2: M=4096 N=2048 K=4096 (MX-fp8)
//   x[:, perm[i]] = zp*exp(log_s)+mu ; log_det exact via fused h.wsum2
//
// R22 (vs R21 PASS @178.4us): gemm2f counted-vmcnt on the VALIDATED dbuf
// geometry (T4, surgical). R21's loop drained vmcnt(0) at __syncthreads
// every K-step (tile t+1's HBM loads ~900cy vs ~350cy compute -> ~20%+
// stall, m97/m233). New loop, geometry untouched (128x64-pair tile,
// 2x32KB dbuf, 256thr, 2 blocks/CU):
//   prologue STAGE(buf0,t0)+STAGE(buf1,t1);
//   loop t: vmcnt(8) (last iter: 0) -> s_barrier -> ds_read buf[t&1] ->
//           setprio(1) MFMA setprio(0) ->
//           if t+2<NT: s_barrier -> STAGE(buf[t&1], t+2)
// Tile t+1's 8 loads stay in flight across the whole iteration (no drain).
// Overwrite safe: bar2 follows every wave's lgkm-gated MFMAs. vmcnt math:
// 16 outstanding at top, vmcnt(8) retires exactly tile t. Raw asm
// s_barrier ("memory") -> no compiler-inserted vmcnt(0).
// R21 note: cross-run rocprof clocks varied 1.33x (R6 profile showed the
// byte-identical R18 kernel at 60us/1600GBps vs 45.3/2133) — wall time is
// authoritative; counters compared within-run only.
// prep_k / gemm1_k byte-identical to R21 (validated).
// ---------------------------------------------------------------------------

typedef float   f32x4  __attribute__((ext_vector_type(4)));
typedef int     i32x4  __attribute__((ext_vector_type(4)));
typedef int     i32x8  __attribute__((ext_vector_type(8)));

__device__ __forceinline__ uint8_t f2fp8(float f) {
    int p = __builtin_amdgcn_cvt_pk_fp8_f32(f, 0.0f, 0, false);
    return (uint8_t)(p & 0xff);
}
__device__ __forceinline__ int8_t f2i8(float v, float s) {
    float q = rintf(v * s);
    q = fminf(fmaxf(q, -127.0f), 127.0f);
    return (int8_t)q;
}

#define GLD16(g, l)                                                          \
    __builtin_amdgcn_global_load_lds(                                        \
        (const __attribute__((address_space(1))) uint32_t*)(g),              \
        (__attribute__((address_space(3))) uint32_t*)(l), 16, 0, 0)

#define MFMA_MX(a, b, c)                                                     \
    __builtin_amdgcn_mfma_scale_f32_16x16x128_f8f6f4(                        \
        (a), (b), (c), 0, 0, 0, 0x7F7F7F7F, 0, 0x7F7F7F7F)

// ---------------------------------------------------------------------------
// prep_k: fused preprocessing, block-role partitioned (unchanged from R21).
// ---------------------------------------------------------------------------
__global__ __launch_bounds__(256) void prep_k(
    const float* __restrict__ W1, int8_t* __restrict__ W1mT,
    const float* __restrict__ W2, uint8_t* __restrict__ W2mT,
    float* __restrict__ ws2p,
    const float* __restrict__ z, const int* __restrict__ perm,
    int8_t* __restrict__ zp, float* __restrict__ ld,
    int D, int H, int B) {
    const int bx  = blockIdx.x;
    const int tid = threadIdx.x;
    const int NB1 = (H / 64) * (D / 64);          // 1024
    const int NB2 = (2 * D / 64) * (H / 64);      // 2048

    if (bx < NB1) {
        // ---- mt1: masked transpose W1 -> int8 (float4 loads) ----
        __shared__ int8_t t[64][68];
        const int c0 = (bx % (H / 64)) * 64;      // col in [0,H)
        const int r0 = (bx / (H / 64)) * 64;      // row in [0,D)
        const int q  = tid & 15;                  // float4-col group
        const int r  = tid >> 4;                  // row phase 0..15

        const int fid = bx * 256 + tid;
        if (fid < B) ld[fid] = 0.0f;

#pragma unroll
        for (int rr0 = 0; rr0 < 64; rr0 += 16) {
            const int rr  = rr0 + r;
            const int row = r0 + rr;
            const float4 v4 =
                *(const float4*)&W1[(size_t)row * H + c0 + q * 4];
            const float vv[4] = {v4.x, v4.y, v4.z, v4.w};
            union { int8_t b4[4]; uint32_t u; } pk;
#pragma unroll
            for (int j = 0; j < 4; j++) {
                const int c = c0 + q * 4 + j;
                pk.b4[j] = ((c % (D - 1)) >= row) ? f2i8(vv[j], 1024.0f)
                                                  : (int8_t)0;
            }
            *(uint32_t*)&t[rr][q * 4] = pk.u;
        }
        __syncthreads();
#pragma unroll
        for (int pass = 0; pass < 2; pass++) {
            const int cc = pass * 32 + (tid >> 3);
            const int j0 = (tid & 7) * 8;
            union { int8_t b[8]; uint64_t qq; } v;
#pragma unroll
            for (int j = 0; j < 8; j++) v.b[j] = t[j0 + j][cc];
            *(uint64_t*)&W1mT[(size_t)(c0 + cc) * D + r0 + j0] = v.qq;
        }
    } else if (bx < NB1 + NB2) {
        // ---- mt2: masked transpose W2 -> fp8 + ws2 partials (float4) ----
        __shared__ uint8_t t[64][68];
        const int idx = bx - NB1;
        const int c0 = (idx % (2 * D / 64)) * 64; // col in [0,2D)
        const int r0 = (idx / (2 * D / 64)) * 64; // row in [0,H)
        const int q  = tid & 15;
        const int r  = tid >> 4;
        const bool second = (c0 >= D);
        const int cb = (c0 - D) >> 6;             // partial slot [0,16)

#pragma unroll
        for (int rr0 = 0; rr0 < 64; rr0 += 16) {
            const int rr  = rr0 + r;
            const int row = r0 + rr;
            const float4 v4 =
                *(const float4*)&W2[(size_t)row * 2 * D + c0 + q * 4];
            const float vv[4] = {v4.x, v4.y, v4.z, v4.w};
            union { uint8_t b4[4]; uint32_t u; } pk;
            float s = 0.0f;
#pragma unroll
            for (int j = 0; j < 4; j++) {
                const int c = c0 + q * 4 + j;
                const bool keep = ((c % D) > (row % (D - 1)));
                pk.b4[j] = keep ? f2fp8(vv[j] * 256.0f) : (uint8_t)0;
                s += keep ? vv[j] : 0.0f;
            }
            *(uint32_t*)&t[rr][q * 4] = pk.u;
            if (second) {
                // threads holding row rr are 16 consecutive lanes
#pragma unroll
                for (int o = 8; o > 0; o >>= 1) s += __shfl_down(s, o, 16);
                if (q == 0) ws2p[(size_t)cb * H + row] = s;
            }
        }
        __syncthreads();
#pragma unroll
        for (int pass = 0; pass < 2; pass++) {
            const int cc = pass * 32 + (tid >> 3);
            const int j0 = (tid & 7) * 8;
            union { uint8_t b[8]; uint64_t qq; } v;
#pragma unroll
            for (int j = 0; j < 8; j++) v.b[j] = t[j0 + j][cc];
            *(uint64_t*)&W2mT[(size_t)(c0 + cc) * H + r0 + j0] = v.qq;
        }
    } else {
        // ---- perm+quant: 2 rows/block, 4 elems/thread/row ----
        const int bp = bx - NB1 - NB2;
        const int i0 = tid * 4;                   // D = 1024 = 256*4
        const int4 p4 = *(const int4*)(perm + i0);
#pragma unroll
        for (int rr = 0; rr < 2; rr++) {
            const int b = bp * 2 + rr;
            const float* zr = z + (size_t)b * D;
            union { int8_t b4[4]; uint32_t u; } q;
            q.b4[0] = f2i8(zr[p4.x], 32.0f);
            q.b4[1] = f2i8(zr[p4.y], 32.0f);
            q.b4[2] = f2i8(zr[p4.z], 32.0f);
            q.b4[3] = f2i8(zr[p4.w], 32.0f);
            *(uint32_t*)&zp[(size_t)b * D + i0] = q.u;
        }
    }
}

// ---------------------------------------------------------------------------
// GEMM1 (int8, K=64/MFMA, BK=128, 32KB LDS):
//   h = fp8(relu(acc/32768 + b1)) + fused exact partial log-det (f32 h).
// (byte-identical to R21 — validated)
// ---------------------------------------------------------------------------
__global__ __launch_bounds__(256) void gemm1_k(
    const int8_t* __restrict__ A, const int8_t* __restrict__ Bt,
    const float* __restrict__ bias, const float* __restrict__ ws2p,
    uint8_t* __restrict__ Cout, float* __restrict__ ld,
    int M, int N, int K) {
    __shared__ __align__(16) int8_t Alds[128 * 128];
    __shared__ __align__(16) int8_t Blds[128 * 128];
    __shared__ float pdl[128];

    const int id   = blockIdx.x;
    const int xcd  = id & 7, s = id >> 3;     // s in [0,128)
    const int mb   = s & 31;
    const int nb   = xcd * 4 + (s >> 5);
    const int m0   = mb * 128;
    const int n0   = nb * 128;

    const int tid  = threadIdx.x;
    const int lane = tid & 63;
    const int w    = tid >> 6;
    const int wm   = (w & 1) * 64;
    const int wn   = (w >> 1) * 64;
    const int quad = lane >> 4;
    const int l16  = lane & 15;

    i32x4 acc[4][4];
#pragma unroll
    for (int i = 0; i < 4; i++)
#pragma unroll
        for (int j = 0; j < 4; j++) acc[i][j] = (i32x4)0;

    const int8_t* Ag[4];
    const int8_t* Bg[4];
    int8_t *Al[4], *Bl[4];
#pragma unroll
    for (int k = 0; k < 4; k++) {
        const int c  = tid + k * 256;
        const int so = ((c & 7) ^ ((c >> 3) & 7)) * 16;  // bytes
        Ag[k] = A + (size_t)(m0 + (c >> 3)) * K + so;
        Bg[k] = Bt + (size_t)(n0 + (c >> 3)) * K + so;
        Al[k] = &Alds[c * 16];
        Bl[k] = &Blds[c * 16];
    }

    const int sw   = l16 & 7;
    const int arow = (wm + l16) * 128;
    const int brow = (wn + l16) * 128;

    for (int kt = 0; kt < K; kt += 128) {
        __syncthreads();
#pragma unroll
        for (int k = 0; k < 4; k++) {
            GLD16(Ag[k] + kt, Al[k]);
            GLD16(Bg[k] + kt, Bl[k]);
        }
        __syncthreads();

#pragma unroll
        for (int kh = 0; kh < 2; kh++) {
            const int pc = ((kh * 4 + quad) ^ sw) * 16;
            i32x4 af[4], bfr[4];
#pragma unroll
            for (int mi = 0; mi < 4; mi++)
                af[mi] = *(const i32x4*)&Alds[arow + mi * 16 * 128 + pc];
#pragma unroll
            for (int ni = 0; ni < 4; ni++)
                bfr[ni] = *(const i32x4*)&Blds[brow + ni * 16 * 128 + pc];
#pragma unroll
            for (int mi = 0; mi < 4; mi++)
#pragma unroll
                for (int ni = 0; ni < 4; ni++)
                    acc[mi][ni] = __builtin_amdgcn_mfma_i32_16x16x64_i8(
                        af[mi], bfr[ni], acc[mi][ni], 0, 0, 0);
        }
    }

    // epilogue: C/D layout col = lane&15, row = quad*4 + reg;  h = acc/32768+b
    const float inv = 1.0f / 32768.0f;
    float bv[4], wv[4];
#pragma unroll
    for (int ni = 0; ni < 4; ni++) {
        const int col = n0 + wn + ni * 16 + l16;
        bv[ni] = bias[col];
        float sv = 0.0f;
#pragma unroll
        for (int cb = 0; cb < 16; cb++) sv += ws2p[(size_t)cb * N + col];
        wv[ni] = sv;
    }
    float pd[4][4];
#pragma unroll
    for (int mi = 0; mi < 4; mi++)
#pragma unroll
        for (int r = 0; r < 4; r++) pd[mi][r] = 0.0f;

#pragma unroll
    for (int mi = 0; mi < 4; mi++) {
        const int row = m0 + wm + mi * 16 + quad * 4;
#pragma unroll
        for (int ni = 0; ni < 4; ni++) {
            const int col = n0 + wn + ni * 16 + l16;
#pragma unroll
            for (int r = 0; r < 4; r++) {
                float v = fmaxf((float)acc[mi][ni][r] * inv + bv[ni], 0.0f);
                pd[mi][r] += v * wv[ni];
                Cout[(size_t)(row + r) * N + col] = f2fp8(v);
            }
        }
    }

#pragma unroll
    for (int off = 1; off < 16; off <<= 1)
#pragma unroll
        for (int mi = 0; mi < 4; mi++)
#pragma unroll
            for (int r = 0; r < 4; r++)
                pd[mi][r] += __shfl_xor(pd[mi][r], off, 16);

    __syncthreads();
    if ((w >> 1) == 0 && l16 == 0)
#pragma unroll
        for (int mi = 0; mi < 4; mi++)
#pragma unroll
            for (int r = 0; r < 4; r++)
                pdl[wm + mi * 16 + quad * 4 + r] = pd[mi][r];
    __syncthreads();
    if ((w >> 1) == 1 && l16 == 0)
#pragma unroll
        for (int mi = 0; mi < 4; mi++)
#pragma unroll
            for (int r = 0; r < 4; r++)
                pdl[wm + mi * 16 + quad * 4 + r] += pd[mi][r];
    __syncthreads();
    if (tid < 128) atomicAdd(&ld[m0 + tid], pdl[tid]);
}

// ---------------------------------------------------------------------------
// GEMM2 fused (MX fp8, K=128/MFMA, BK=128, 64KB LDS dbuf, counted vmcnt):
//   geometry identical to R18-validated: block = 128 rows x 64 col-pairs,
//   B-tile rows 0-63 = mu cols, 64-127 = ls cols; epilogue x = z*exp(ls)+mu.
//   Sync structure = T4 counted schedule (see header). nb==0 -> log_det.
// ---------------------------------------------------------------------------
__global__ __launch_bounds__(256) void gemm2f_k(
    const uint8_t* __restrict__ A, const uint8_t* __restrict__ Bt,
    const float* __restrict__ b2, const int* __restrict__ perm,
    const float* __restrict__ z, const float* __restrict__ ld,
    float* __restrict__ out, int B, int D, int K) {
    __shared__ __align__(16) uint8_t Alds[2][128 * 128];
    __shared__ __align__(16) uint8_t Blds[2][128 * 128];
    __shared__ float red[4];

    const int id   = blockIdx.x;
    const int nb   = id & 15;         // col-pair block [0,16)
    const int s    = id >> 4;         // m-block [0,32)
    const int m0   = s * 128;
    const int p0   = nb * 64;         // col-pair base

    const int tid  = threadIdx.x;
    const int lane = tid & 63;
    const int w    = tid >> 6;
    const int wm   = (w & 1) * 64;    // wave rows
    const int wp   = (w >> 1) * 32;   // wave col-pairs
    const int quad = lane >> 4;
    const int l16  = lane & 15;

    f32x4 acc[4][4];
#pragma unroll
    for (int i = 0; i < 4; i++)
#pragma unroll
        for (int j = 0; j < 4; j++) acc[i][j] = (f32x4)0.0f;

    // staging: A = 128 rows x 128B, B = 128 rows x 128B (4 chunks/thread ea)
    const uint8_t* Ag[4];
    const uint8_t* Bg[4];
    int ldso[4];
#pragma unroll
    for (int k = 0; k < 4; k++) {
        const int c  = tid + k * 256;
        const int r  = c >> 3;
        const int so = ((c & 7) ^ (r & 7)) * 16;  // bytes
        Ag[k] = A + (size_t)(m0 + r) * K + so;
        const int g = (r < 64) ? (p0 + r) : (D + p0 + (r - 64));
        Bg[k] = Bt + (size_t)g * K + so;
        ldso[k] = c * 16;
    }

    const int sw   = l16 & 7;
    const int pc0  = ((quad * 2) ^ sw) * 16;
    const int pc1  = ((quad * 2 + 1) ^ sw) * 16;

    // prologue: stage K-tiles 0 and 1 (16 loads/thread in flight)
#pragma unroll
    for (int k = 0; k < 4; k++) {
        GLD16(Ag[k], &Alds[0][ldso[k]]);
        GLD16(Bg[k], &Blds[0][ldso[k]]);
    }
#pragma unroll
    for (int k = 0; k < 4; k++) {
        GLD16(Ag[k] + 128, &Alds[1][ldso[k]]);
        GLD16(Bg[k] + 128, &Blds[1][ldso[k]]);
    }

    const int NT = K / 128;   // 32
    for (int t = 0; t < NT; ++t) {
        // retire exactly tile t's 8 loads; tile t+1's stay in flight
        if (t < NT - 1) {
            asm volatile("s_waitcnt vmcnt(8)" ::: "memory");
        } else {
            asm volatile("s_waitcnt vmcnt(0)" ::: "memory");
        }
        asm volatile("s_barrier" ::: "memory");

        const int cur = t & 1;
        union ABu { int4 h2[2]; i32x8 v; };
        i32x8 af[4], bfr[4];
#pragma unroll
        for (int mi = 0; mi < 4; mi++) {
            ABu tt;
            const int ar = (wm + mi * 16 + l16) * 128;
            tt.h2[0] = *(const int4*)&Alds[cur][ar + pc0];
            tt.h2[1] = *(const int4*)&Alds[cur][ar + pc1];
            af[mi] = tt.v;
        }
#pragma unroll
        for (int ni = 0; ni < 4; ni++) {
            ABu tt;
            const int br = ((ni >> 1) * 64 + wp + (ni & 1) * 16 + l16) * 128;
            tt.h2[0] = *(const int4*)&Blds[cur][br + pc0];
            tt.h2[1] = *(const int4*)&Blds[cur][br + pc1];
            bfr[ni] = tt.v;
        }
        __builtin_amdgcn_s_setprio(1);
#pragma unroll
        for (int mi = 0; mi < 4; mi++)
#pragma unroll
            for (int ni = 0; ni < 4; ni++)
                acc[mi][ni] = MFMA_MX(af[mi], bfr[ni], acc[mi][ni]);
        __builtin_amdgcn_s_setprio(0);

        if (t + 2 < NT) {
            // all waves' lgkm-gated reads of buf[cur] are done -> safe to
            // overwrite with tile t+2 (loads span the next iteration)
            asm volatile("s_barrier" ::: "memory");
#pragma unroll
            for (int k = 0; k < 4; k++) {
                GLD16(Ag[k] + (t + 2) * 128, &Alds[cur][ldso[k]]);
                GLD16(Bg[k] + (t + 2) * 128, &Blds[cur][ldso[k]]);
            }
        }
    }

    // fused epilogue: mu = acc[mi][ci]/256 + b2[c]; ls = acc[mi][ci+2]/256
    //  + b2[D+c] (clamped); x[row][perm[c]] = z[row][perm[c]]*exp(ls)+mu.
    const float inv = 1.0f / 256.0f;
    float bmu[2], bls[2];
    int   pcv[2];
#pragma unroll
    for (int ci = 0; ci < 2; ci++) {
        const int gc = p0 + wp + ci * 16 + l16;
        bmu[ci] = b2[gc];
        bls[ci] = b2[D + gc];
        pcv[ci] = perm[gc];
    }
#pragma unroll
    for (int mi = 0; mi < 4; mi++) {
        const int row0 = m0 + wm + mi * 16 + quad * 4;
#pragma unroll
        for (int ci = 0; ci < 2; ci++) {
#pragma unroll
            for (int r = 0; r < 4; r++) {
                const size_t idx = (size_t)(row0 + r) * D + pcv[ci];
                const float mu = acc[mi][ci][r] * inv + bmu[ci];
                float ls = acc[mi][ci + 2][r] * inv + bls[ci];
                ls = fminf(fmaxf(ls, -30.0f), 30.0f);
                out[idx] = z[idx] * expf(ls) + mu;
            }
        }
    }

    // log_det: out[B*D + b] = ld[b] + sum(b2[D:2D))   (nb==0 blocks only)
    if (nb == 0) {
        float bs = 0.0f;
        for (int i = tid; i < D; i += 256) bs += b2[D + i];
#pragma unroll
        for (int o = 32; o > 0; o >>= 1) bs += __shfl_down(bs, o, 64);
        if ((tid & 63) == 0) red[tid >> 6] = bs;
        __syncthreads();
        if (tid < 128)
            out[(size_t)B * D + m0 + tid] =
                ld[m0 + tid] + red[0] + red[1] + red[2] + red[3];
    }
}

// ---------------------------------------------------------------------------
extern "C" void kernel_launch(void* const* d_in, const int* in_sizes, int n_in,
                              void* d_out, int out_size, void* d_ws, size_t ws_size,
                              hipStream_t stream) {
    const float* z    = (const float*)d_in[0];
    const float* W1   = (const float*)d_in[1];
    const float* b1   = (const float*)d_in[2];
    const float* W2   = (const float*)d_in[3];
    const float* b2   = (const float*)d_in[4];
    const int*   perm = (const int*)d_in[5];
    float* out = (float*)d_out;
    char*  ws  = (char*)d_ws;

    const int D = in_sizes[5];          // 1024
    const int H = in_sizes[2];          // 4096
    const int B = in_sizes[0] / D;      // 4096

    const size_t off_h    = 0;                                  // B*H fp8 16MB
    const size_t off_W2mT = off_h    + (size_t)B * H;           // 2D*H fp8 8MB
    const size_t off_W1mT = off_W2mT + (size_t)2 * D * H;       // H*D i8  4MB
    const size_t off_zp   = off_W1mT + (size_t)H * D;           // B*D i8  4MB
    const size_t off_ws2  = off_zp   + (size_t)B * D;           // 16*H*4 256KB
    const size_t off_ld   = off_ws2  + (size_t)16 * H * 4;      // B*4

    uint8_t* h    = (uint8_t*)(ws + off_h);
    uint8_t* W2mT = (uint8_t*)(ws + off_W2mT);
    int8_t*  W1mT = (int8_t*)(ws + off_W1mT);
    int8_t*  zp   = (int8_t*)(ws + off_zp);
    float*   ws2p = (float*)(ws + off_ws2);
    float*   ld   = (float*)(ws + off_ld);

    // fused preprocessing: mt1 (+ ld zero) | mt2 (+ ws2 partials) | perm
    const int NB1 = (H / 64) * (D / 64);       // 1024
    const int NB2 = (2 * D / 64) * (H / 64);   // 2048
    const int NBP = B / 2;                     // 2048
    prep_k<<<NB1 + NB2 + NBP, 256, 0, stream>>>(
        W1, W1mT, W2, W2mT, ws2p, z, perm, zp, ld, D, H, B);

    // h = fp8(relu((zp @ W1m)/32768 + b1)) + fused ld partials [M=B,N=H,K=D]
    gemm1_k<<<(H / 128) * (B / 128), 256, 0, stream>>>(
        zp, W1mT, b1, ws2p, h, ld, B, H, D);

    // fused: x = z*exp(log_s)+mu scattered by perm; log_det from ld.
    //   [M=B rows x D col-pairs, K=H]  grid = (D/64)*(B/128) = 512
    gemm2f_k<<<(D / 64) * (B / 128), 256, 0, stream>>>(
        h, W2mT, b2, perm, z, ld, out, B, D, H);
}

// Round 8
// 168.498 us; speedup vs baseline: 1.1802x; 1.0212x over previous
//
#include <hip/hip_runtime.h>
#include <stdint.h>

// ---------------------------------------------------------------------------
// MADE flow layer, f32 I/O.
//   h  = relu(zp @ (W1*M1) + b1)     GEMM1: M=4096 N=4096 K=1024 (int8)
//   res= h @ (W2*M2) + b2            GEMM2: M=4096 N=2048 K=4096 (MX-fp8)
//   x[:, perm[i]] = zp*exp(log_s)+mu ; log_det exact via fused h.wsum2
//
// R23 (vs R22 PASS @172.1us): port the R22-VALIDATED counted-vmcnt dbuf
// schedule to gemm1. R22 proved T4-on-unchanged-geometry works (gemm2f
// dropped out of the top-5; profile now dominated by harness fillBuffer
// dispatches we can't touch). gemm1 still ran the single-buffer 2-barrier
// loop with a vmcnt(0) drain per K-step (8 steps, ~350cy compute vs
// ~900cy HBM). gemm1 has the identical staging shape (8x GLD16/thread
// per 32KB K-tile) -> same schedule verbatim:
//   prologue STAGE(buf0,t0)+STAGE(buf1,t1);
//   loop t: vmcnt(8) (last: 0) -> s_barrier -> ds_read buf[t&1] ->
//           setprio(1) MFMA setprio(0) ->
//           if t+2<NT: s_barrier -> STAGE(buf[t&1], t+2)
// LDS 2x32KB (+pdl) = still 2 blocks/CU. Arithmetic bit-identical.
// prep_k / gemm2f_k byte-identical to R22 (validated).
// ---------------------------------------------------------------------------

typedef float   f32x4  __attribute__((ext_vector_type(4)));
typedef int     i32x4  __attribute__((ext_vector_type(4)));
typedef int     i32x8  __attribute__((ext_vector_type(8)));

__device__ __forceinline__ uint8_t f2fp8(float f) {
    int p = __builtin_amdgcn_cvt_pk_fp8_f32(f, 0.0f, 0, false);
    return (uint8_t)(p & 0xff);
}
__device__ __forceinline__ int8_t f2i8(float v, float s) {
    float q = rintf(v * s);
    q = fminf(fmaxf(q, -127.0f), 127.0f);
    return (int8_t)q;
}

#define GLD16(g, l)                                                          \
    __builtin_amdgcn_global_load_lds(                                        \
        (const __attribute__((address_space(1))) uint32_t*)(g),              \
        (__attribute__((address_space(3))) uint32_t*)(l), 16, 0, 0)

#define MFMA_MX(a, b, c)                                                     \
    __builtin_amdgcn_mfma_scale_f32_16x16x128_f8f6f4(                        \
        (a), (b), (c), 0, 0, 0, 0x7F7F7F7F, 0, 0x7F7F7F7F)

// ---------------------------------------------------------------------------
// prep_k: fused preprocessing, block-role partitioned (unchanged from R21).
// ---------------------------------------------------------------------------
__global__ __launch_bounds__(256) void prep_k(
    const float* __restrict__ W1, int8_t* __restrict__ W1mT,
    const float* __restrict__ W2, uint8_t* __restrict__ W2mT,
    float* __restrict__ ws2p,
    const float* __restrict__ z, const int* __restrict__ perm,
    int8_t* __restrict__ zp, float* __restrict__ ld,
    int D, int H, int B) {
    const int bx  = blockIdx.x;
    const int tid = threadIdx.x;
    const int NB1 = (H / 64) * (D / 64);          // 1024
    const int NB2 = (2 * D / 64) * (H / 64);      // 2048

    if (bx < NB1) {
        // ---- mt1: masked transpose W1 -> int8 (float4 loads) ----
        __shared__ int8_t t[64][68];
        const int c0 = (bx % (H / 64)) * 64;      // col in [0,H)
        const int r0 = (bx / (H / 64)) * 64;      // row in [0,D)
        const int q  = tid & 15;                  // float4-col group
        const int r  = tid >> 4;                  // row phase 0..15

        const int fid = bx * 256 + tid;
        if (fid < B) ld[fid] = 0.0f;

#pragma unroll
        for (int rr0 = 0; rr0 < 64; rr0 += 16) {
            const int rr  = rr0 + r;
            const int row = r0 + rr;
            const float4 v4 =
                *(const float4*)&W1[(size_t)row * H + c0 + q * 4];
            const float vv[4] = {v4.x, v4.y, v4.z, v4.w};
            union { int8_t b4[4]; uint32_t u; } pk;
#pragma unroll
            for (int j = 0; j < 4; j++) {
                const int c = c0 + q * 4 + j;
                pk.b4[j] = ((c % (D - 1)) >= row) ? f2i8(vv[j], 1024.0f)
                                                  : (int8_t)0;
            }
            *(uint32_t*)&t[rr][q * 4] = pk.u;
        }
        __syncthreads();
#pragma unroll
        for (int pass = 0; pass < 2; pass++) {
            const int cc = pass * 32 + (tid >> 3);
            const int j0 = (tid & 7) * 8;
            union { int8_t b[8]; uint64_t qq; } v;
#pragma unroll
            for (int j = 0; j < 8; j++) v.b[j] = t[j0 + j][cc];
            *(uint64_t*)&W1mT[(size_t)(c0 + cc) * D + r0 + j0] = v.qq;
        }
    } else if (bx < NB1 + NB2) {
        // ---- mt2: masked transpose W2 -> fp8 + ws2 partials (float4) ----
        __shared__ uint8_t t[64][68];
        const int idx = bx - NB1;
        const int c0 = (idx % (2 * D / 64)) * 64; // col in [0,2D)
        const int r0 = (idx / (2 * D / 64)) * 64; // row in [0,H)
        const int q  = tid & 15;
        const int r  = tid >> 4;
        const bool second = (c0 >= D);
        const int cb = (c0 - D) >> 6;             // partial slot [0,16)

#pragma unroll
        for (int rr0 = 0; rr0 < 64; rr0 += 16) {
            const int rr  = rr0 + r;
            const int row = r0 + rr;
            const float4 v4 =
                *(const float4*)&W2[(size_t)row * 2 * D + c0 + q * 4];
            const float vv[4] = {v4.x, v4.y, v4.z, v4.w};
            union { uint8_t b4[4]; uint32_t u; } pk;
            float s = 0.0f;
#pragma unroll
            for (int j = 0; j < 4; j++) {
                const int c = c0 + q * 4 + j;
                const bool keep = ((c % D) > (row % (D - 1)));
                pk.b4[j] = keep ? f2fp8(vv[j] * 256.0f) : (uint8_t)0;
                s += keep ? vv[j] : 0.0f;
            }
            *(uint32_t*)&t[rr][q * 4] = pk.u;
            if (second) {
                // threads holding row rr are 16 consecutive lanes
#pragma unroll
                for (int o = 8; o > 0; o >>= 1) s += __shfl_down(s, o, 16);
                if (q == 0) ws2p[(size_t)cb * H + row] = s;
            }
        }
        __syncthreads();
#pragma unroll
        for (int pass = 0; pass < 2; pass++) {
            const int cc = pass * 32 + (tid >> 3);
            const int j0 = (tid & 7) * 8;
            union { uint8_t b[8]; uint64_t qq; } v;
#pragma unroll
            for (int j = 0; j < 8; j++) v.b[j] = t[j0 + j][cc];
            *(uint64_t*)&W2mT[(size_t)(c0 + cc) * H + r0 + j0] = v.qq;
        }
    } else {
        // ---- perm+quant: 2 rows/block, 4 elems/thread/row ----
        const int bp = bx - NB1 - NB2;
        const int i0 = tid * 4;                   // D = 1024 = 256*4
        const int4 p4 = *(const int4*)(perm + i0);
#pragma unroll
        for (int rr = 0; rr < 2; rr++) {
            const int b = bp * 2 + rr;
            const float* zr = z + (size_t)b * D;
            union { int8_t b4[4]; uint32_t u; } q;
            q.b4[0] = f2i8(zr[p4.x], 32.0f);
            q.b4[1] = f2i8(zr[p4.y], 32.0f);
            q.b4[2] = f2i8(zr[p4.z], 32.0f);
            q.b4[3] = f2i8(zr[p4.w], 32.0f);
            *(uint32_t*)&zp[(size_t)b * D + i0] = q.u;
        }
    }
}

// ---------------------------------------------------------------------------
// GEMM1 (int8, K=64/MFMA, BK=128, 2x32KB LDS dbuf, counted vmcnt):
//   h = fp8(relu(acc/32768 + b1)) + fused exact partial log-det (f32 h).
//   Geometry identical to the R21-validated kernel; sync structure = the
//   R22-validated T4 counted schedule (see header).
// ---------------------------------------------------------------------------
__global__ __launch_bounds__(256) void gemm1_k(
    const int8_t* __restrict__ A, const int8_t* __restrict__ Bt,
    const float* __restrict__ bias, const float* __restrict__ ws2p,
    uint8_t* __restrict__ Cout, float* __restrict__ ld,
    int M, int N, int K) {
    __shared__ __align__(16) int8_t Alds[2][128 * 128];
    __shared__ __align__(16) int8_t Blds[2][128 * 128];
    __shared__ float pdl[128];

    const int id   = blockIdx.x;
    const int xcd  = id & 7, s = id >> 3;     // s in [0,128)
    const int mb   = s & 31;
    const int nb   = xcd * 4 + (s >> 5);
    const int m0   = mb * 128;
    const int n0   = nb * 128;

    const int tid  = threadIdx.x;
    const int lane = tid & 63;
    const int w    = tid >> 6;
    const int wm   = (w & 1) * 64;
    const int wn   = (w >> 1) * 64;
    const int quad = lane >> 4;
    const int l16  = lane & 15;

    i32x4 acc[4][4];
#pragma unroll
    for (int i = 0; i < 4; i++)
#pragma unroll
        for (int j = 0; j < 4; j++) acc[i][j] = (i32x4)0;

    const int8_t* Ag[4];
    const int8_t* Bg[4];
    int ldso[4];
#pragma unroll
    for (int k = 0; k < 4; k++) {
        const int c  = tid + k * 256;
        const int so = ((c & 7) ^ ((c >> 3) & 7)) * 16;  // bytes
        Ag[k] = A + (size_t)(m0 + (c >> 3)) * K + so;
        Bg[k] = Bt + (size_t)(n0 + (c >> 3)) * K + so;
        ldso[k] = c * 16;
    }

    const int sw   = l16 & 7;
    const int arow = (wm + l16) * 128;
    const int brow = (wn + l16) * 128;

    // prologue: stage K-tiles 0 and 1 (16 loads/thread in flight)
#pragma unroll
    for (int k = 0; k < 4; k++) {
        GLD16(Ag[k], &Alds[0][ldso[k]]);
        GLD16(Bg[k], &Blds[0][ldso[k]]);
    }
#pragma unroll
    for (int k = 0; k < 4; k++) {
        GLD16(Ag[k] + 128, &Alds[1][ldso[k]]);
        GLD16(Bg[k] + 128, &Blds[1][ldso[k]]);
    }

    const int NT = K / 128;   // 8
    for (int t = 0; t < NT; ++t) {
        if (t < NT - 1) {
            asm volatile("s_waitcnt vmcnt(8)" ::: "memory");
        } else {
            asm volatile("s_waitcnt vmcnt(0)" ::: "memory");
        }
        asm volatile("s_barrier" ::: "memory");

        const int cur = t & 1;
#pragma unroll
        for (int kh = 0; kh < 2; kh++) {
            const int pc = ((kh * 4 + quad) ^ sw) * 16;
            i32x4 af[4], bfr[4];
#pragma unroll
            for (int mi = 0; mi < 4; mi++)
                af[mi] = *(const i32x4*)&Alds[cur][arow + mi * 16 * 128 + pc];
#pragma unroll
            for (int ni = 0; ni < 4; ni++)
                bfr[ni] = *(const i32x4*)&Blds[cur][brow + ni * 16 * 128 + pc];
            __builtin_amdgcn_s_setprio(1);
#pragma unroll
            for (int mi = 0; mi < 4; mi++)
#pragma unroll
                for (int ni = 0; ni < 4; ni++)
                    acc[mi][ni] = __builtin_amdgcn_mfma_i32_16x16x64_i8(
                        af[mi], bfr[ni], acc[mi][ni], 0, 0, 0);
            __builtin_amdgcn_s_setprio(0);
        }

        if (t + 2 < NT) {
            // all waves' lgkm-gated reads of buf[cur] done -> safe overwrite
            asm volatile("s_barrier" ::: "memory");
#pragma unroll
            for (int k = 0; k < 4; k++) {
                GLD16(Ag[k] + (t + 2) * 128, &Alds[cur][ldso[k]]);
                GLD16(Bg[k] + (t + 2) * 128, &Blds[cur][ldso[k]]);
            }
        }
    }

    // epilogue: C/D layout col = lane&15, row = quad*4 + reg;  h = acc/32768+b
    const float inv = 1.0f / 32768.0f;
    float bv[4], wv[4];
#pragma unroll
    for (int ni = 0; ni < 4; ni++) {
        const int col = n0 + wn + ni * 16 + l16;
        bv[ni] = bias[col];
        float sv = 0.0f;
#pragma unroll
        for (int cb = 0; cb < 16; cb++) sv += ws2p[(size_t)cb * N + col];
        wv[ni] = sv;
    }
    float pd[4][4];
#pragma unroll
    for (int mi = 0; mi < 4; mi++)
#pragma unroll
        for (int r = 0; r < 4; r++) pd[mi][r] = 0.0f;

#pragma unroll
    for (int mi = 0; mi < 4; mi++) {
        const int row = m0 + wm + mi * 16 + quad * 4;
#pragma unroll
        for (int ni = 0; ni < 4; ni++) {
            const int col = n0 + wn + ni * 16 + l16;
#pragma unroll
            for (int r = 0; r < 4; r++) {
                float v = fmaxf((float)acc[mi][ni][r] * inv + bv[ni], 0.0f);
                pd[mi][r] += v * wv[ni];
                Cout[(size_t)(row + r) * N + col] = f2fp8(v);
            }
        }
    }

#pragma unroll
    for (int off = 1; off < 16; off <<= 1)
#pragma unroll
        for (int mi = 0; mi < 4; mi++)
#pragma unroll
            for (int r = 0; r < 4; r++)
                pd[mi][r] += __shfl_xor(pd[mi][r], off, 16);

    __syncthreads();
    if ((w >> 1) == 0 && l16 == 0)
#pragma unroll
        for (int mi = 0; mi < 4; mi++)
#pragma unroll
            for (int r = 0; r < 4; r++)
                pdl[wm + mi * 16 + quad * 4 + r] = pd[mi][r];
    __syncthreads();
    if ((w >> 1) == 1 && l16 == 0)
#pragma unroll
        for (int mi = 0; mi < 4; mi++)
#pragma unroll
            for (int r = 0; r < 4; r++)
                pdl[wm + mi * 16 + quad * 4 + r] += pd[mi][r];
    __syncthreads();
    if (tid < 128) atomicAdd(&ld[m0 + tid], pdl[tid]);
}

// ---------------------------------------------------------------------------
// GEMM2 fused (MX fp8, K=128/MFMA, BK=128, 64KB LDS dbuf, counted vmcnt):
//   geometry identical to R18-validated: block = 128 rows x 64 col-pairs,
//   B-tile rows 0-63 = mu cols, 64-127 = ls cols; epilogue x = z*exp(ls)+mu.
//   Sync structure = T4 counted schedule. nb==0 -> log_det.
//   (byte-identical to R22 — validated)
// ---------------------------------------------------------------------------
__global__ __launch_bounds__(256) void gemm2f_k(
    const uint8_t* __restrict__ A, const uint8_t* __restrict__ Bt,
    const float* __restrict__ b2, const int* __restrict__ perm,
    const float* __restrict__ z, const float* __restrict__ ld,
    float* __restrict__ out, int B, int D, int K) {
    __shared__ __align__(16) uint8_t Alds[2][128 * 128];
    __shared__ __align__(16) uint8_t Blds[2][128 * 128];
    __shared__ float red[4];

    const int id   = blockIdx.x;
    const int nb   = id & 15;         // col-pair block [0,16)
    const int s    = id >> 4;         // m-block [0,32)
    const int m0   = s * 128;
    const int p0   = nb * 64;         // col-pair base

    const int tid  = threadIdx.x;
    const int lane = tid & 63;
    const int w    = tid >> 6;
    const int wm   = (w & 1) * 64;    // wave rows
    const int wp   = (w >> 1) * 32;   // wave col-pairs
    const int quad = lane >> 4;
    const int l16  = lane & 15;

    f32x4 acc[4][4];
#pragma unroll
    for (int i = 0; i < 4; i++)
#pragma unroll
        for (int j = 0; j < 4; j++) acc[i][j] = (f32x4)0.0f;

    // staging: A = 128 rows x 128B, B = 128 rows x 128B (4 chunks/thread ea)
    const uint8_t* Ag[4];
    const uint8_t* Bg[4];
    int ldso[4];
#pragma unroll
    for (int k = 0; k < 4; k++) {
        const int c  = tid + k * 256;
        const int r  = c >> 3;
        const int so = ((c & 7) ^ (r & 7)) * 16;  // bytes
        Ag[k] = A + (size_t)(m0 + r) * K + so;
        const int g = (r < 64) ? (p0 + r) : (D + p0 + (r - 64));
        Bg[k] = Bt + (size_t)g * K + so;
        ldso[k] = c * 16;
    }

    const int sw   = l16 & 7;
    const int pc0  = ((quad * 2) ^ sw) * 16;
    const int pc1  = ((quad * 2 + 1) ^ sw) * 16;

    // prologue: stage K-tiles 0 and 1 (16 loads/thread in flight)
#pragma unroll
    for (int k = 0; k < 4; k++) {
        GLD16(Ag[k], &Alds[0][ldso[k]]);
        GLD16(Bg[k], &Blds[0][ldso[k]]);
    }
#pragma unroll
    for (int k = 0; k < 4; k++) {
        GLD16(Ag[k] + 128, &Alds[1][ldso[k]]);
        GLD16(Bg[k] + 128, &Blds[1][ldso[k]]);
    }

    const int NT = K / 128;   // 32
    for (int t = 0; t < NT; ++t) {
        // retire exactly tile t's 8 loads; tile t+1's stay in flight
        if (t < NT - 1) {
            asm volatile("s_waitcnt vmcnt(8)" ::: "memory");
        } else {
            asm volatile("s_waitcnt vmcnt(0)" ::: "memory");
        }
        asm volatile("s_barrier" ::: "memory");

        const int cur = t & 1;
        union ABu { int4 h2[2]; i32x8 v; };
        i32x8 af[4], bfr[4];
#pragma unroll
        for (int mi = 0; mi < 4; mi++) {
            ABu tt;
            const int ar = (wm + mi * 16 + l16) * 128;
            tt.h2[0] = *(const int4*)&Alds[cur][ar + pc0];
            tt.h2[1] = *(const int4*)&Alds[cur][ar + pc1];
            af[mi] = tt.v;
        }
#pragma unroll
        for (int ni = 0; ni < 4; ni++) {
            ABu tt;
            const int br = ((ni >> 1) * 64 + wp + (ni & 1) * 16 + l16) * 128;
            tt.h2[0] = *(const int4*)&Blds[cur][br + pc0];
            tt.h2[1] = *(const int4*)&Blds[cur][br + pc1];
            bfr[ni] = tt.v;
        }
        __builtin_amdgcn_s_setprio(1);
#pragma unroll
        for (int mi = 0; mi < 4; mi++)
#pragma unroll
            for (int ni = 0; ni < 4; ni++)
                acc[mi][ni] = MFMA_MX(af[mi], bfr[ni], acc[mi][ni]);
        __builtin_amdgcn_s_setprio(0);

        if (t + 2 < NT) {
            // all waves' lgkm-gated reads of buf[cur] are done -> safe to
            // overwrite with tile t+2 (loads span the next iteration)
            asm volatile("s_barrier" ::: "memory");
#pragma unroll
            for (int k = 0; k < 4; k++) {
                GLD16(Ag[k] + (t + 2) * 128, &Alds[cur][ldso[k]]);
                GLD16(Bg[k] + (t + 2) * 128, &Blds[cur][ldso[k]]);
            }
        }
    }

    // fused epilogue: mu = acc[mi][ci]/256 + b2[c]; ls = acc[mi][ci+2]/256
    //  + b2[D+c] (clamped); x[row][perm[c]] = z[row][perm[c]]*exp(ls)+mu.
    const float inv = 1.0f / 256.0f;
    float bmu[2], bls[2];
    int   pcv[2];
#pragma unroll
    for (int ci = 0; ci < 2; ci++) {
        const int gc = p0 + wp + ci * 16 + l16;
        bmu[ci] = b2[gc];
        bls[ci] = b2[D + gc];
        pcv[ci] = perm[gc];
    }
#pragma unroll
    for (int mi = 0; mi < 4; mi++) {
        const int row0 = m0 + wm + mi * 16 + quad * 4;
#pragma unroll
        for (int ci = 0; ci < 2; ci++) {
#pragma unroll
            for (int r = 0; r < 4; r++) {
                const size_t idx = (size_t)(row0 + r) * D + pcv[ci];
                const float mu = acc[mi][ci][r] * inv + bmu[ci];
                float ls = acc[mi][ci + 2][r] * inv + bls[ci];
                ls = fminf(fmaxf(ls, -30.0f), 30.0f);
                out[idx] = z[idx] * expf(ls) + mu;
            }
        }
    }

    // log_det: out[B*D + b] = ld[b] + sum(b2[D:2D))   (nb==0 blocks only)
    if (nb == 0) {
        float bs = 0.0f;
        for (int i = tid; i < D; i += 256) bs += b2[D + i];
#pragma unroll
        for (int o = 32; o > 0; o >>= 1) bs += __shfl_down(bs, o, 64);
        if ((tid & 63) == 0) red[tid >> 6] = bs;
        __syncthreads();
        if (tid < 128)
            out[(size_t)B * D + m0 + tid] =
                ld[m0 + tid] + red[0] + red[1] + red[2] + red[3];
    }
}

// ---------------------------------------------------------------------------
extern "C" void kernel_launch(void* const* d_in, const int* in_sizes, int n_in,
                              void* d_out, int out_size, void* d_ws, size_t ws_size,
                              hipStream_t stream) {
    const float* z    = (const float*)d_in[0];
    const float* W1   = (const float*)d_in[1];
    const float* b1   = (const float*)d_in[2];
    const float* W2   = (const float*)d_in[3];
    const float* b2   = (const float*)d_in[4];
    const int*   perm = (const int*)d_in[5];
    float* out = (float*)d_out;
    char*  ws  = (char*)d_ws;

    const int D = in_sizes[5];          // 1024
    const int H = in_sizes[2];          // 4096
    const int B = in_sizes[0] / D;      // 4096

    const size_t off_h    = 0;                                  // B*H fp8 16MB
    const size_t off_W2mT = off_h    + (size_t)B * H;           // 2D*H fp8 8MB
    const size_t off_W1mT = off_W2mT + (size_t)2 * D * H;       // H*D i8  4MB
    const size_t off_zp   = off_W1mT + (size_t)H * D;           // B*D i8  4MB
    const size_t off_ws2  = off_zp   + (size_t)B * D;           // 16*H*4 256KB
    const size_t off_ld   = off_ws2  + (size_t)16 * H * 4;      // B*4

    uint8_t* h    = (uint8_t*)(ws + off_h);
    uint8_t* W2mT = (uint8_t*)(ws + off_W2mT);
    int8_t*  W1mT = (int8_t*)(ws + off_W1mT);
    int8_t*  zp   = (int8_t*)(ws + off_zp);
    float*   ws2p = (float*)(ws + off_ws2);
    float*   ld   = (float*)(ws + off_ld);

    // fused preprocessing: mt1 (+ ld zero) | mt2 (+ ws2 partials) | perm
    const int NB1 = (H / 64) * (D / 64);       // 1024
    const int NB2 = (2 * D / 64) * (H / 64);   // 2048
    const int NBP = B / 2;                     // 2048
    prep_k<<<NB1 + NB2 + NBP, 256, 0, stream>>>(
        W1, W1mT, W2, W2mT, ws2p, z, perm, zp, ld, D, H, B);

    // h = fp8(relu((zp @ W1m)/32768 + b1)) + fused ld partials [M=B,N=H,K=D]
    gemm1_k<<<(H / 128) * (B / 128), 256, 0, stream>>>(
        zp, W1mT, b1, ws2p, h, ld, B, H, D);

    // fused: x = z*exp(log_s)+mu scattered by perm; log_det from ld.
    //   [M=B rows x D col-pairs, K=H]  grid = (D/64)*(B/128) = 512
    gemm2f_k<<<(D / 64) * (B / 128), 256, 0, stream>>>(
        h, W2mT, b2, perm, z, ld, out, B, D, H);
}